// Round 6
// baseline (4938.599 us; speedup 1.0000x reference)
//
#include <hip/hip_runtime.h>
#include <hip/hip_cooperative_groups.h>
#include <math.h>

namespace cg = cooperative_groups;

#define T_TOTAL 32000
#define BATCH 4
#define TT 64
#define TTF 32

typedef __bf16 bf16x8 __attribute__((ext_vector_type(8)));
typedef float f32x4 __attribute__((ext_vector_type(4)));
typedef unsigned int uint4v __attribute__((ext_vector_type(4)));
typedef unsigned int uint2v __attribute__((ext_vector_type(2)));

__device__ __forceinline__ unsigned short f2b(float f) {
    unsigned int u = __float_as_uint(f);
    u += 0x7FFFu + ((u >> 16) & 1u);
    return (unsigned short)(u >> 16);
}
__device__ __forceinline__ unsigned int f2b2(float lo, float hi) {
    return (unsigned int)f2b(lo) | ((unsigned int)f2b(hi) << 16);
}
__device__ __forceinline__ bf16x8 ld_bf8(const unsigned short* p) {
    return __builtin_bit_cast(bf16x8, *(const uint4v*)p);
}
__device__ __forceinline__ float fast_sigmoid(float x) {
    return __builtin_amdgcn_rcpf(1.0f + __expf(-x));
}
__device__ __forceinline__ float fast_tanh(float x) {
    return 1.0f - 2.0f * __builtin_amdgcn_rcpf(1.0f + __expf(2.0f * x));
}

// ---------------- weight packing (fp32 -> bf16, fused/padded layouts) ----------
__global__ void k_pack(const float* __restrict__ conv_w, const float* __restrict__ cond_w,
                       const float* __restrict__ skip_w, const float* __restrict__ out_w,
                       const float* __restrict__ first_w, const float* __restrict__ last1_w,
                       const float* __restrict__ last2_w, const float* __restrict__ skip_b,
                       unsigned short* __restrict__ wgp, unsigned short* __restrict__ wzp,
                       unsigned short* __restrict__ fwp, unsigned short* __restrict__ l1p,
                       unsigned short* __restrict__ l2p, float* __restrict__ sbs) {
    int i = blockIdx.x * blockDim.x + threadIdx.x;
    if (i < 860160) {  // wgp: 30*128*224
        int l = i / 28672, r = i % 28672;
        int o = r / 224, k = r % 224;
        float v;
        if (k < 64)       v = conv_w[(((size_t)l * 128 + o) * 64 + k) * 2 + 0];
        else if (k < 128) v = conv_w[(((size_t)l * 128 + o) * 64 + (k - 64)) * 2 + 1];
        else if (k < 208) v = cond_w[((size_t)l * 128 + o) * 80 + (k - 128)];
        else              v = 0.0f;
        wgp[i] = f2b(v);
        return;
    }
    i -= 860160;
    if (i < 245760) {  // wzp: 30*128*64 (skip rows 0..63, out rows 64..127)
        int l = i / 8192, rr = (i % 8192) / 64, k = i % 64;
        float v = (rr < 64) ? skip_w[((size_t)l * 64 + rr) * 64 + k]
                            : out_w[((size_t)l * 64 + (rr - 64)) * 64 + k];
        wzp[i] = f2b(v);
        return;
    }
    i -= 245760;
    if (i < 16384) { fwp[i] = f2b(first_w[i]); return; }   // 64*256
    i -= 16384;
    if (i < 4096) { l1p[i] = f2b(last1_w[i]); return; }    // 64*64
    i -= 4096;
    if (i < 16384) { l2p[i] = f2b(last2_w[i]); return; }   // 256*64
    i -= 16384;
    if (i < 64) {
        float a = 0.f;
        for (int l = 0; l < 30; ++l) a += skip_b[l * 64 + i];
        sbs[i] = a;
    }
}

// ---------------- upsample network ----------------
__global__ void k_convin(const float* __restrict__ c, const float* __restrict__ w,
                         float* __restrict__ c1) {
    int idx = blockIdx.x * blockDim.x + threadIdx.x;
    if (idx >= BATCH * 80 * 400) return;
    int f = idx % 400;
    int o = (idx / 400) % 80;
    int b = idx / (400 * 80);
    const float* cb = c + (size_t)b * 80 * 400 + f;
    const float* wr = w + o * 80;
    float acc = 0.f;
    #pragma unroll 8
    for (int j = 0; j < 80; ++j) acc += wr[j] * cb[(size_t)j * 400];
    c1[idx] = acc;
}

__global__ void k_up0(const float* __restrict__ c1, const float* __restrict__ w,
                      float* __restrict__ c2) {
    int idx = blockIdx.x * blockDim.x + threadIdx.x;
    if (idx >= BATCH * 80 * 4000) return;
    int t = idx % 4000;
    int ch = idx / 4000;
    int u = t / 10, r = t - u * 10;
    float w0 = 0.f, w1 = 0.f, w2 = 0.f;
    #pragma unroll
    for (int j = 0; j < 21; ++j) {
        float wj = w[j];
        int a = r - 10 + j;
        if (a < 0) w0 += wj;
        else if (a < 10) w1 += wj;
        else w2 += wj;
    }
    const float* src = c1 + (size_t)ch * 400;
    float s0 = (u >= 1) ? src[u - 1] : 0.f;
    float s1 = src[u];
    float s2 = (u + 1 < 400) ? src[u + 1] : 0.f;
    c2[idx] = w0 * s0 + w1 * s1 + w2 * s2;
}

__global__ __launch_bounds__(256) void k_up1b(const float* __restrict__ c2,
                                              const float* __restrict__ w,
                                              unsigned short* __restrict__ cupb) {
    __shared__ float S[80][13];
    __shared__ float W[8][4];
    const int b = blockIdx.y, t0 = blockIdx.x * 64;
    const int tid = threadIdx.x;
    const int u0 = t0 >> 3;

    for (int i = tid; i < 800; i += 256) {
        int ch = i / 10, uu = i % 10;
        int u = u0 - 1 + uu;
        float v = 0.f;
        if (u >= 0 && u < 4000) v = c2[((size_t)b * 80 + ch) * 4000 + u];
        S[ch][uu] = v;
    }
    if (tid < 24) {
        int r = tid / 3, k = tid % 3;
        int jlo = (k == 0) ? 0 : (k == 1 ? 8 - r : 16 - r);
        int jhi = (k == 0) ? 7 - r : (k == 1 ? 15 - r : 16);
        float a = 0.f;
        for (int j = jlo; j <= jhi; ++j) a += w[j];
        W[r][k] = a;
    }
    __syncthreads();

    unsigned short* ob = cupb + ((size_t)b * T_TOTAL + t0) * 96;
    for (int i = tid; i < 64 * 96; i += 256) {
        int ch = i % 96;
        int tl = i / 96;
        float acc = 0.f;
        if (ch < 80) {
            int r = tl & 7, ub = tl >> 3;
            acc = W[r][0] * S[ch][ub] + W[r][1] * S[ch][ub + 1] + W[r][2] * S[ch][ub + 2];
        }
        ob[i] = f2b(acc);
    }
}

// ---------------- first 1x1 conv (MFMA), TTF=32 tile for occupancy -----------
#define XFS 266
__global__ __launch_bounds__(256, 8) void k_first(
    const float* __restrict__ x, const unsigned short* __restrict__ fwp,
    const float* __restrict__ fb, float* __restrict__ h0) {
    __shared__ unsigned short Xf[TTF * XFS];
    const int b = blockIdx.y, t0 = blockIdx.x * TTF, tid = threadIdx.x;
    const int lane = tid & 63;
    const int wv = __builtin_amdgcn_readfirstlane(tid >> 6);
    const int l15 = lane & 15, q = lane >> 4;

    for (int i = tid; i < 2048; i += 256) {
        int ch = i >> 3;
        int t4 = (i & 7) << 2;
        const float* xr = x + ((size_t)b * 256 + ch) * T_TOTAL + t0 + t4;
        float4 u = *(const float4*)xr;
        int base = t4 * XFS + ch;
        Xf[base + 0 * XFS] = f2b(u.x);
        Xf[base + 1 * XFS] = f2b(u.y);
        Xf[base + 2 * XFS] = f2b(u.z);
        Xf[base + 3 * XFS] = f2b(u.w);
    }
    __syncthreads();

    f32x4 acc[2] = {};
    const unsigned short* wr = fwp + (size_t)(16 * wv + l15) * 256;
    #pragma unroll
    for (int ks = 0; ks < 8; ++ks) {
        bf16x8 aA = ld_bf8(wr + ks * 32 + q * 8);
        #pragma unroll
        for (int tt = 0; tt < 2; ++tt) {
            bf16x8 bb = ld_bf8(&Xf[(tt * 16 + l15) * XFS + ks * 32 + q * 8]);
            acc[tt] = __builtin_amdgcn_mfma_f32_16x16x32_bf16(aA, bb, acc[tt], 0, 0, 0);
        }
    }
    const float4 fbv = *(const float4*)&fb[16 * wv + 4 * q];
    float* hob = h0 + (size_t)b * T_TOTAL * 64;
    #pragma unroll
    for (int tt = 0; tt < 2; ++tt) {
        size_t base = (size_t)(t0 + tt * 16 + l15) * 64 + 16 * wv + 4 * q;
        float4 ho;
        ho.x = acc[tt][0] + fbv.x;
        ho.y = acc[tt][1] + fbv.y;
        ho.z = acc[tt][2] + fbv.z;
        ho.w = acc[tt][3] + fbv.w;
        *(float4*)(hob + base) = ho;
    }
}

// ---------------- persistent-kernel building blocks --------------------------
// One WaveNet layer on one 64-t tile. Skip contribution accumulates into the
// caller's persistent register accumulator accS (fp32 MFMA C operand).
__device__ __forceinline__ void layer_tile(
    const float* __restrict__ hb, float* __restrict__ hob,
    const unsigned short* __restrict__ cbb,
    const unsigned short* __restrict__ wgp_l, const unsigned short* __restrict__ wzp_l,
    const float* __restrict__ cb_l, const float* __restrict__ ob_l,
    int t0, int d, int tid, int wv, int l15, int q,
    unsigned short* __restrict__ Xl, unsigned short* __restrict__ zs,
    f32x4 (&accS)[4], int writeH) {
    // stage taps (fp32 -> bf16)
    for (int i = tid; i < 512; i += 256) {
        int t = i >> 3, cb8 = (i & 7) << 3;
        const float4* p1 = (const float4*)(hb + (size_t)(t0 + t) * 64 + cb8);
        float4 u0 = p1[0], u1 = p1[1];
        uint4v v1;
        v1.x = f2b2(u0.x, u0.y); v1.y = f2b2(u0.z, u0.w);
        v1.z = f2b2(u1.x, u1.y); v1.w = f2b2(u1.z, u1.w);
        *(uint4v*)&Xl[t * 224 + 64 + cb8] = v1;
        int td = t0 + t - d;
        uint4v v0 = {0u, 0u, 0u, 0u};
        if (td >= 0) {
            const float4* p0 = (const float4*)(hb + (size_t)td * 64 + cb8);
            float4 w0 = p0[0], w1 = p0[1];
            v0.x = f2b2(w0.x, w0.y); v0.y = f2b2(w0.z, w0.w);
            v0.z = f2b2(w1.x, w1.y); v0.w = f2b2(w1.z, w1.w);
        }
        *(uint4v*)&Xl[t * 224 + cb8] = v0;
    }
    // stage conditioning (already bf16, zero-padded ch 80..95)
    for (int i = tid; i < 768; i += 256) {
        int t = i / 12, j = (i % 12) << 3;
        *(uint4v*)&Xl[t * 224 + 128 + j] = *(const uint4v*)&cbb[(size_t)(t0 + t) * 96 + j];
    }
    __syncthreads();

    // gate GEMM
    f32x4 accA[4] = {}, accG[4] = {};
    const unsigned short* wrow_a = wgp_l + (size_t)(16 * wv + l15) * 224;
    const unsigned short* wrow_g = wgp_l + (size_t)(64 + 16 * wv + l15) * 224;
    #pragma unroll
    for (int ks = 0; ks < 7; ++ks) {
        bf16x8 aA = ld_bf8(wrow_a + ks * 32 + q * 8);
        bf16x8 aG = ld_bf8(wrow_g + ks * 32 + q * 8);
        #pragma unroll
        for (int tt = 0; tt < 4; ++tt) {
            bf16x8 bb = ld_bf8(&Xl[(tt * 16 + l15) * 224 + ks * 32 + q * 8]);
            accA[tt] = __builtin_amdgcn_mfma_f32_16x16x32_bf16(aA, bb, accA[tt], 0, 0, 0);
            accG[tt] = __builtin_amdgcn_mfma_f32_16x16x32_bf16(aG, bb, accG[tt], 0, 0, 0);
        }
    }
    const float4 cbA = *(const float4*)&cb_l[16 * wv + 4 * q];
    const float4 cbG = *(const float4*)&cb_l[64 + 16 * wv + 4 * q];
    #pragma unroll
    for (int tt = 0; tt < 4; ++tt) {
        int t = tt * 16 + l15;
        float z0 = fast_tanh(accA[tt][0] + cbA.x) * fast_sigmoid(accG[tt][0] + cbG.x);
        float z1 = fast_tanh(accA[tt][1] + cbA.y) * fast_sigmoid(accG[tt][1] + cbG.y);
        float z2 = fast_tanh(accA[tt][2] + cbA.z) * fast_sigmoid(accG[tt][2] + cbG.z);
        float z3 = fast_tanh(accA[tt][3] + cbA.w) * fast_sigmoid(accG[tt][3] + cbG.w);
        uint2v zv;
        zv.x = f2b2(z0, z1);
        zv.y = f2b2(z2, z3);
        *(uint2v*)&zs[t * 72 + 16 * wv + 4 * q] = zv;
    }
    __syncthreads();  // fences all Xl reads -> next tile may restage Xl safely

    // skip GEMM into persistent accS (+ out GEMM & residual write unless last)
    const unsigned short* zrow_s = wzp_l + (size_t)(16 * wv + l15) * 64;
    if (writeH) {
        f32x4 accO[4] = {};
        const unsigned short* zrow_o = wzp_l + (size_t)(64 + 16 * wv + l15) * 64;
        #pragma unroll
        for (int ks = 0; ks < 2; ++ks) {
            bf16x8 aS = ld_bf8(zrow_s + ks * 32 + q * 8);
            bf16x8 aO = ld_bf8(zrow_o + ks * 32 + q * 8);
            #pragma unroll
            for (int tt = 0; tt < 4; ++tt) {
                bf16x8 bb = ld_bf8(&zs[(tt * 16 + l15) * 72 + ks * 32 + q * 8]);
                accS[tt] = __builtin_amdgcn_mfma_f32_16x16x32_bf16(aS, bb, accS[tt], 0, 0, 0);
                accO[tt] = __builtin_amdgcn_mfma_f32_16x16x32_bf16(aO, bb, accO[tt], 0, 0, 0);
            }
        }
        const float4 obv = *(const float4*)&ob_l[16 * wv + 4 * q];
        #pragma unroll
        for (int tt = 0; tt < 4; ++tt) {
            size_t base = (size_t)(t0 + tt * 16 + l15) * 64 + 16 * wv + 4 * q;
            float4 hi = *(const float4*)(hb + base);
            float4 ho;
            ho.x = hi.x + accO[tt][0] + obv.x;
            ho.y = hi.y + accO[tt][1] + obv.y;
            ho.z = hi.z + accO[tt][2] + obv.z;
            ho.w = hi.w + accO[tt][3] + obv.w;
            *(float4*)(hob + base) = ho;
        }
    } else {
        #pragma unroll
        for (int ks = 0; ks < 2; ++ks) {
            bf16x8 aS = ld_bf8(zrow_s + ks * 32 + q * 8);
            #pragma unroll
            for (int tt = 0; tt < 4; ++tt) {
                bf16x8 bb = ld_bf8(&zs[(tt * 16 + l15) * 72 + ks * 32 + q * 8]);
                accS[tt] = __builtin_amdgcn_mfma_f32_16x16x32_bf16(aS, bb, accS[tt], 0, 0, 0);
            }
        }
    }
}

// relu(accS + sbs) -> last1 -> relu -> last2 -> out, for one tile.
__device__ __forceinline__ void last_tile(
    f32x4 (&accS)[4], const float* __restrict__ sbs,
    const unsigned short* __restrict__ l1p, const float* __restrict__ b1,
    const unsigned short* __restrict__ l2p, const float* __restrict__ b2,
    float* __restrict__ ob, int t0, int tid, int wv, int l15, int q,
    unsigned short* __restrict__ zt, unsigned short* __restrict__ o2s) {
    const float4 sbv = *(const float4*)&sbs[16 * wv + 4 * q];
    #pragma unroll
    for (int tt = 0; tt < 4; ++tt) {
        int t = tt * 16 + l15;
        float s0 = fmaxf(accS[tt][0] + sbv.x, 0.f);
        float s1 = fmaxf(accS[tt][1] + sbv.y, 0.f);
        float s2 = fmaxf(accS[tt][2] + sbv.z, 0.f);
        float s3 = fmaxf(accS[tt][3] + sbv.w, 0.f);
        uint2v zv;
        zv.x = f2b2(s0, s1);
        zv.y = f2b2(s2, s3);
        *(uint2v*)&zt[t * 72 + 16 * wv + 4 * q] = zv;
    }
    __syncthreads();

    f32x4 a1[4] = {};
    const unsigned short* w1r = l1p + (size_t)(16 * wv + l15) * 64;
    #pragma unroll
    for (int ks = 0; ks < 2; ++ks) {
        bf16x8 aA = ld_bf8(w1r + ks * 32 + q * 8);
        #pragma unroll
        for (int tt = 0; tt < 4; ++tt) {
            bf16x8 bb = ld_bf8(&zt[(tt * 16 + l15) * 72 + ks * 32 + q * 8]);
            a1[tt] = __builtin_amdgcn_mfma_f32_16x16x32_bf16(aA, bb, a1[tt], 0, 0, 0);
        }
    }
    const float4 b1v = *(const float4*)&b1[16 * wv + 4 * q];
    #pragma unroll
    for (int tt = 0; tt < 4; ++tt) {
        int t = tt * 16 + l15;
        float z0 = fmaxf(a1[tt][0] + b1v.x, 0.f);
        float z1 = fmaxf(a1[tt][1] + b1v.y, 0.f);
        float z2 = fmaxf(a1[tt][2] + b1v.z, 0.f);
        float z3 = fmaxf(a1[tt][3] + b1v.w, 0.f);
        uint2v zv;
        zv.x = f2b2(z0, z1);
        zv.y = f2b2(z2, z3);
        *(uint2v*)&o2s[t * 72 + 16 * wv + 4 * q] = zv;
    }
    __syncthreads();

    f32x4 a2[4][4] = {};
    #pragma unroll
    for (int ks = 0; ks < 2; ++ks) {
        bf16x8 aw[4];
        #pragma unroll
        for (int j = 0; j < 4; ++j)
            aw[j] = ld_bf8(l2p + (size_t)(64 * wv + 16 * j + l15) * 64 + ks * 32 + q * 8);
        #pragma unroll
        for (int tt = 0; tt < 4; ++tt) {
            bf16x8 bb = ld_bf8(&o2s[(tt * 16 + l15) * 72 + ks * 32 + q * 8]);
            #pragma unroll
            for (int j = 0; j < 4; ++j)
                a2[j][tt] = __builtin_amdgcn_mfma_f32_16x16x32_bf16(aw[j], bb, a2[j][tt], 0, 0, 0);
        }
    }
    #pragma unroll
    for (int j = 0; j < 4; ++j) {
        int o0 = 64 * wv + 16 * j + 4 * q;
        float4 b2v = *(const float4*)&b2[o0];
        #pragma unroll
        for (int tt = 0; tt < 4; ++tt) {
            int t = t0 + tt * 16 + l15;
            ob[(size_t)(o0 + 0) * T_TOTAL + t] = a2[j][tt][0] + b2v.x;
            ob[(size_t)(o0 + 1) * T_TOTAL + t] = a2[j][tt][1] + b2v.y;
            ob[(size_t)(o0 + 2) * T_TOTAL + t] = a2[j][tt][2] + b2v.z;
            ob[(size_t)(o0 + 3) * T_TOTAL + t] = a2[j][tt][3] + b2v.w;
        }
    }
}

// ---------------- persistent cooperative kernel: all 30 layers + last --------
// grid = 1000 blocks x 256 thr, each block owns 2 (b,tile) pairs; skip
// accumulators live in registers across all layers (no skips memory traffic).
__global__ __launch_bounds__(256, 4) void k_wavenet(
    float* __restrict__ hA, float* __restrict__ hB,
    const unsigned short* __restrict__ cupb,
    const unsigned short* __restrict__ wgp, const unsigned short* __restrict__ wzp,
    const float* __restrict__ conv_b, const float* __restrict__ out_b,
    const float* __restrict__ sbs,
    const unsigned short* __restrict__ l1p, const float* __restrict__ b1,
    const unsigned short* __restrict__ l2p, const float* __restrict__ b2,
    float* __restrict__ out) {
    cg::grid_group grid = cg::this_grid();
    __shared__ unsigned short Xl[64 * 224];
    __shared__ unsigned short zs[64 * 72];
    const int tid = threadIdx.x;
    const int lane = tid & 63;
    const int wv = __builtin_amdgcn_readfirstlane(tid >> 6);
    const int l15 = lane & 15, q = lane >> 4;
    const int b = blockIdx.x & 3;
    const int p = blockIdx.x >> 2;        // 0..249
    const int t0A = p * 64;
    const int t0B = (p + 250) * 64;

    const unsigned short* cbb = cupb + (size_t)b * T_TOTAL * 96;
    float* hin = hA + (size_t)b * T_TOTAL * 64;
    float* hout = hB + (size_t)b * T_TOTAL * 64;

    f32x4 accSA[4] = {}, accSB[4] = {};

    for (int l = 0; l < 30; ++l) {
        const int d = 1 << (l % 10);
        const unsigned short* wgp_l = wgp + (size_t)l * 128 * 224;
        const unsigned short* wzp_l = wzp + (size_t)l * 8192;
        const float* cb_l = conv_b + (size_t)l * 128;
        const float* ob_l = out_b + (size_t)l * 64;
        const int wH = (l != 29);
        layer_tile(hin, hout, cbb, wgp_l, wzp_l, cb_l, ob_l, t0A, d,
                   tid, wv, l15, q, Xl, zs, accSA, wH);
        layer_tile(hin, hout, cbb, wgp_l, wzp_l, cb_l, ob_l, t0B, d,
                   tid, wv, l15, q, Xl, zs, accSB, wH);
        if (l != 29) {
            grid.sync();
            float* tmp = hin; hin = hout; hout = tmp;
        }
    }

    float* ob = out + (size_t)b * 256 * T_TOTAL;
    last_tile(accSA, sbs, l1p, b1, l2p, b2, ob, t0A, tid, wv, l15, q, Xl, zs);
    last_tile(accSB, sbs, l1p, b1, l2p, b2, ob, t0B, tid, wv, l15, q, Xl, zs);
}

// ---------------- fallback full layer (with fp32 skip accumulation) ----------
__global__ __launch_bounds__(256, 4) void k_layer_f(
    const float* __restrict__ h_in, float* __restrict__ h_out,
    float* __restrict__ skips, const unsigned short* __restrict__ cupb,
    const unsigned short* __restrict__ wgp, const unsigned short* __restrict__ wzp,
    const float* __restrict__ cb_l, const float* __restrict__ ob_l,
    const float* __restrict__ sb_l, int d, int first) {
    __shared__ unsigned short Xl[64 * 224];
    __shared__ unsigned short zs[64 * 72];
    const int b = blockIdx.y, t0 = blockIdx.x * TT, tid = threadIdx.x;
    const int lane = tid & 63;
    const int wv = __builtin_amdgcn_readfirstlane(tid >> 6);
    const int l15 = lane & 15, q = lane >> 4;

    const float* hb = h_in + (size_t)b * T_TOTAL * 64;
    for (int i = tid; i < 512; i += 256) {
        int t = i >> 3, cb8 = (i & 7) << 3;
        const float4* p1 = (const float4*)(hb + (size_t)(t0 + t) * 64 + cb8);
        float4 u0 = p1[0], u1 = p1[1];
        uint4v v1;
        v1.x = f2b2(u0.x, u0.y); v1.y = f2b2(u0.z, u0.w);
        v1.z = f2b2(u1.x, u1.y); v1.w = f2b2(u1.z, u1.w);
        *(uint4v*)&Xl[t * 224 + 64 + cb8] = v1;
        int td = t0 + t - d;
        uint4v v0 = {0u, 0u, 0u, 0u};
        if (td >= 0) {
            const float4* p0 = (const float4*)(hb + (size_t)td * 64 + cb8);
            float4 w0 = p0[0], w1 = p0[1];
            v0.x = f2b2(w0.x, w0.y); v0.y = f2b2(w0.z, w0.w);
            v0.z = f2b2(w1.x, w1.y); v0.w = f2b2(w1.z, w1.w);
        }
        *(uint4v*)&Xl[t * 224 + cb8] = v0;
    }
    const unsigned short* cbb = cupb + (size_t)b * T_TOTAL * 96;
    for (int i = tid; i < 768; i += 256) {
        int t = i / 12, j = (i % 12) << 3;
        *(uint4v*)&Xl[t * 224 + 128 + j] = *(const uint4v*)&cbb[(size_t)(t0 + t) * 96 + j];
    }
    __syncthreads();

    f32x4 accA[4] = {}, accG[4] = {};
    const unsigned short* wrow_a = wgp + (size_t)(16 * wv + l15) * 224;
    const unsigned short* wrow_g = wgp + (size_t)(64 + 16 * wv + l15) * 224;
    #pragma unroll
    for (int ks = 0; ks < 7; ++ks) {
        bf16x8 aA = ld_bf8(wrow_a + ks * 32 + q * 8);
        bf16x8 aG = ld_bf8(wrow_g + ks * 32 + q * 8);
        #pragma unroll
        for (int tt = 0; tt < 4; ++tt) {
            bf16x8 bb = ld_bf8(&Xl[(tt * 16 + l15) * 224 + ks * 32 + q * 8]);
            accA[tt] = __builtin_amdgcn_mfma_f32_16x16x32_bf16(aA, bb, accA[tt], 0, 0, 0);
            accG[tt] = __builtin_amdgcn_mfma_f32_16x16x32_bf16(aG, bb, accG[tt], 0, 0, 0);
        }
    }
    const float4 cbA = *(const float4*)&cb_l[16 * wv + 4 * q];
    const float4 cbG = *(const float4*)&cb_l[64 + 16 * wv + 4 * q];
    #pragma unroll
    for (int tt = 0; tt < 4; ++tt) {
        int t = tt * 16 + l15;
        float z0 = fast_tanh(accA[tt][0] + cbA.x) * fast_sigmoid(accG[tt][0] + cbG.x);
        float z1 = fast_tanh(accA[tt][1] + cbA.y) * fast_sigmoid(accG[tt][1] + cbG.y);
        float z2 = fast_tanh(accA[tt][2] + cbA.z) * fast_sigmoid(accG[tt][2] + cbG.z);
        float z3 = fast_tanh(accA[tt][3] + cbA.w) * fast_sigmoid(accG[tt][3] + cbG.w);
        uint2v zv;
        zv.x = f2b2(z0, z1);
        zv.y = f2b2(z2, z3);
        *(uint2v*)&zs[t * 72 + 16 * wv + 4 * q] = zv;
    }
    __syncthreads();

    f32x4 accS[4] = {}, accO[4] = {};
    const unsigned short* zrow_s = wzp + (size_t)(16 * wv + l15) * 64;
    const unsigned short* zrow_o = wzp + (size_t)(64 + 16 * wv + l15) * 64;
    #pragma unroll
    for (int ks = 0; ks < 2; ++ks) {
        bf16x8 aS = ld_bf8(zrow_s + ks * 32 + q * 8);
        bf16x8 aO = ld_bf8(zrow_o + ks * 32 + q * 8);
        #pragma unroll
        for (int tt = 0; tt < 4; ++tt) {
            bf16x8 bb = ld_bf8(&zs[(tt * 16 + l15) * 72 + ks * 32 + q * 8]);
            accS[tt] = __builtin_amdgcn_mfma_f32_16x16x32_bf16(aS, bb, accS[tt], 0, 0, 0);
            accO[tt] = __builtin_amdgcn_mfma_f32_16x16x32_bf16(aO, bb, accO[tt], 0, 0, 0);
        }
    }
    const float4 sbv = *(const float4*)&sb_l[16 * wv + 4 * q];
    const float4 obv = *(const float4*)&ob_l[16 * wv + 4 * q];
    float* hob = h_out + (size_t)b * T_TOTAL * 64;
    float* skb = skips + (size_t)b * T_TOTAL * 64;
    #pragma unroll
    for (int tt = 0; tt < 4; ++tt) {
        size_t base = (size_t)(t0 + tt * 16 + l15) * 64 + 16 * wv + 4 * q;
        float4 hi = *(const float4*)(hb + base);
        float4 ho;
        ho.x = hi.x + accO[tt][0] + obv.x;
        ho.y = hi.y + accO[tt][1] + obv.y;
        ho.z = hi.z + accO[tt][2] + obv.z;
        ho.w = hi.w + accO[tt][3] + obv.w;
        *(float4*)(hob + base) = ho;
        float4 sv;
        if (first) {
            sv.x = accS[tt][0] + sbv.x;
            sv.y = accS[tt][1] + sbv.y;
            sv.z = accS[tt][2] + sbv.z;
            sv.w = accS[tt][3] + sbv.w;
        } else {
            float4 sp = *(const float4*)(skb + base);
            sv.x = sp.x + accS[tt][0] + sbv.x;
            sv.y = sp.y + accS[tt][1] + sbv.y;
            sv.z = sp.z + accS[tt][2] + sbv.z;
            sv.w = sp.w + accS[tt][3] + sbv.w;
        }
        *(float4*)(skb + base) = sv;
    }
}

// ---------------- fallback last layers -----------------
__global__ __launch_bounds__(256) void k_last(
    const float* __restrict__ skips, const unsigned short* __restrict__ l1p,
    const float* __restrict__ b1, const unsigned short* __restrict__ l2p,
    const float* __restrict__ b2, float* __restrict__ out) {
    __shared__ unsigned short sp[64 * 72];
    __shared__ unsigned short o2s[64 * 72];
    const int b = blockIdx.y, t0 = blockIdx.x * TT, tid = threadIdx.x;
    const int lane = tid & 63;
    const int wv = __builtin_amdgcn_readfirstlane(tid >> 6);
    const int l15 = lane & 15, q = lane >> 4;

    const float* skb = skips + (size_t)b * T_TOTAL * 64;
    for (int i = tid; i < 512; i += 256) {
        int t = i >> 3, cb8 = (i & 7) << 3;
        const float4* p = (const float4*)(skb + (size_t)(t0 + t) * 64 + cb8);
        float4 u0 = p[0], u1 = p[1];
        uint4v v;
        v.x = f2b2(fmaxf(u0.x, 0.f), fmaxf(u0.y, 0.f));
        v.y = f2b2(fmaxf(u0.z, 0.f), fmaxf(u0.w, 0.f));
        v.z = f2b2(fmaxf(u1.x, 0.f), fmaxf(u1.y, 0.f));
        v.w = f2b2(fmaxf(u1.z, 0.f), fmaxf(u1.w, 0.f));
        *(uint4v*)&sp[t * 72 + cb8] = v;
    }
    __syncthreads();

    f32x4 a1[4] = {};
    const unsigned short* w1r = l1p + (size_t)(16 * wv + l15) * 64;
    #pragma unroll
    for (int ks = 0; ks < 2; ++ks) {
        bf16x8 aA = ld_bf8(w1r + ks * 32 + q * 8);
        #pragma unroll
        for (int tt = 0; tt < 4; ++tt) {
            bf16x8 bb = ld_bf8(&sp[(tt * 16 + l15) * 72 + ks * 32 + q * 8]);
            a1[tt] = __builtin_amdgcn_mfma_f32_16x16x32_bf16(aA, bb, a1[tt], 0, 0, 0);
        }
    }
    const float4 b1v = *(const float4*)&b1[16 * wv + 4 * q];
    #pragma unroll
    for (int tt = 0; tt < 4; ++tt) {
        int t = tt * 16 + l15;
        float z0 = fmaxf(a1[tt][0] + b1v.x, 0.f);
        float z1 = fmaxf(a1[tt][1] + b1v.y, 0.f);
        float z2 = fmaxf(a1[tt][2] + b1v.z, 0.f);
        float z3 = fmaxf(a1[tt][3] + b1v.w, 0.f);
        uint2v zv;
        zv.x = f2b2(z0, z1);
        zv.y = f2b2(z2, z3);
        *(uint2v*)&o2s[t * 72 + 16 * wv + 4 * q] = zv;
    }
    __syncthreads();

    f32x4 a2[4][4] = {};
    #pragma unroll
    for (int ks = 0; ks < 2; ++ks) {
        bf16x8 aw[4];
        #pragma unroll
        for (int j = 0; j < 4; ++j)
            aw[j] = ld_bf8(l2p + (size_t)(64 * wv + 16 * j + l15) * 64 + ks * 32 + q * 8);
        #pragma unroll
        for (int tt = 0; tt < 4; ++tt) {
            bf16x8 bb = ld_bf8(&o2s[(tt * 16 + l15) * 72 + ks * 32 + q * 8]);
            #pragma unroll
            for (int j = 0; j < 4; ++j)
                a2[j][tt] = __builtin_amdgcn_mfma_f32_16x16x32_bf16(aw[j], bb, a2[j][tt], 0, 0, 0);
        }
    }
    float* ob = out + (size_t)b * 256 * T_TOTAL;
    #pragma unroll
    for (int j = 0; j < 4; ++j) {
        int o0 = 64 * wv + 16 * j + 4 * q;
        float4 b2v = *(const float4*)&b2[o0];
        #pragma unroll
        for (int tt = 0; tt < 4; ++tt) {
            int t = t0 + tt * 16 + l15;
            ob[(size_t)(o0 + 0) * T_TOTAL + t] = a2[j][tt][0] + b2v.x;
            ob[(size_t)(o0 + 1) * T_TOTAL + t] = a2[j][tt][1] + b2v.y;
            ob[(size_t)(o0 + 2) * T_TOTAL + t] = a2[j][tt][2] + b2v.z;
            ob[(size_t)(o0 + 3) * T_TOTAL + t] = a2[j][tt][3] + b2v.w;
        }
    }
}

extern "C" void kernel_launch(void* const* d_in, const int* in_sizes, int n_in,
                              void* d_out, int out_size, void* d_ws, size_t ws_size,
                              hipStream_t stream) {
    const float* x         = (const float*)d_in[0];
    const float* c         = (const float*)d_in[1];
    const float* first_w   = (const float*)d_in[2];
    const float* first_b   = (const float*)d_in[3];
    const float* conv_w    = (const float*)d_in[4];
    const float* conv_b    = (const float*)d_in[5];
    const float* out_b     = (const float*)d_in[8];
    const float* cond_w    = (const float*)d_in[6];
    const float* out_w     = (const float*)d_in[7];
    const float* skip_w    = (const float*)d_in[9];
    const float* skip_b    = (const float*)d_in[10];
    const float* last1_w   = (const float*)d_in[11];
    const float* last1_b   = (const float*)d_in[12];
    const float* last2_w   = (const float*)d_in[13];
    const float* last2_b   = (const float*)d_in[14];
    const float* conv_in_w = (const float*)d_in[15];
    const float* up_w0     = (const float*)d_in[16];
    const float* up_w1     = (const float*)d_in[17];

    unsigned char* base = (unsigned char*)d_ws;
    float* c1            = (float*)(base + 0);                   //    512,000
    float* c2            = (float*)(base + 512000);              //  5,120,000
    unsigned short* cupb = (unsigned short*)(base + 5632000);    // 24,576,000
    float* hA            = (float*)(base + 30208000);            // 32,768,000
    float* hB            = (float*)(base + 62976000);            // 32,768,000
    float* skipsP        = (float*)(base + 95744000);            // 32,768,000 (fallback only)
    unsigned short* wgp  = (unsigned short*)(base + 128512000);  //  1,720,320
    unsigned short* wzp  = (unsigned short*)(base + 130232320);  //    491,520
    unsigned short* fwp  = (unsigned short*)(base + 130723840);  //     32,768
    unsigned short* l1p  = (unsigned short*)(base + 130756608);  //      8,192
    unsigned short* l2p  = (unsigned short*)(base + 130764800);  //     32,768
    float* sbs           = (float*)(base + 130797568);           //        256

    k_pack<<<(1142848 + 255) / 256, 256, 0, stream>>>(
        conv_w, cond_w, skip_w, out_w, first_w, last1_w, last2_w, skip_b,
        wgp, wzp, fwp, l1p, l2p, sbs);
    k_convin<<<(BATCH * 80 * 400 + 255) / 256, 256, 0, stream>>>(c, conv_in_w, c1);
    k_up0<<<(BATCH * 80 * 4000 + 255) / 256, 256, 0, stream>>>(c1, up_w0, c2);
    dim3 upg(T_TOTAL / 64, BATCH);
    k_up1b<<<upg, 256, 0, stream>>>(c2, up_w1, cupb);

    dim3 gridF(T_TOTAL / TTF, BATCH);
    k_first<<<gridF, 256, 0, stream>>>(x, fwp, first_b, hA);

    // persistent cooperative path
    float* outp = (float*)d_out;
    void* kargs[] = {(void*)&hA, (void*)&hB, (void*)&cupb, (void*)&wgp, (void*)&wzp,
                     (void*)&conv_b, (void*)&out_b, (void*)&sbs,
                     (void*)&l1p, (void*)&last1_b, (void*)&l2p, (void*)&last2_b,
                     (void*)&outp};
    hipError_t cerr = hipLaunchCooperativeKernel((const void*)k_wavenet,
                                                 dim3(1000), dim3(256),
                                                 kargs, 0, stream);
    if (cerr != hipSuccess) {
        (void)hipGetLastError();  // clear sticky error, fall back to fused path
        dim3 grid(T_TOTAL / TT, BATCH);
        float* hin = hA;
        float* hout = hB;
        for (int l = 0; l < 30; ++l) {
            int d = 1 << (l % 10);
            k_layer_f<<<grid, 256, 0, stream>>>(
                hin, hout, skipsP, cupb,
                wgp + (size_t)l * 128 * 224, wzp + (size_t)l * 128 * 64,
                conv_b + (size_t)l * 128, out_b + (size_t)l * 64, skip_b + (size_t)l * 64,
                d, l == 0 ? 1 : 0);
            float* tmp = hin; hin = hout; hout = tmp;
        }
        k_last<<<grid, 256, 0, stream>>>(skipsP, l1p, last1_b, l2p, last2_b, (float*)d_out);
    }
}

// Round 7
// 1659.470 us; speedup vs baseline: 2.9760x; 2.9760x over previous
//
#include <hip/hip_runtime.h>
#include <math.h>

#define T_TOTAL 32000
#define BATCH 4
#define TT 64
#define TTL 32
#define TTF 32

typedef __bf16 bf16x8 __attribute__((ext_vector_type(8)));
typedef float f32x4 __attribute__((ext_vector_type(4)));
typedef unsigned int uint4v __attribute__((ext_vector_type(4)));
typedef unsigned int uint2v __attribute__((ext_vector_type(2)));

__device__ __forceinline__ unsigned short f2b(float f) {
    unsigned int u = __float_as_uint(f);
    u += 0x7FFFu + ((u >> 16) & 1u);
    return (unsigned short)(u >> 16);
}
__device__ __forceinline__ unsigned int f2b2(float lo, float hi) {
    return (unsigned int)f2b(lo) | ((unsigned int)f2b(hi) << 16);
}
__device__ __forceinline__ bf16x8 ld_bf8(const unsigned short* p) {
    return __builtin_bit_cast(bf16x8, *(const uint4v*)p);
}
__device__ __forceinline__ float fast_sigmoid(float x) {
    return __builtin_amdgcn_rcpf(1.0f + __expf(-x));
}
__device__ __forceinline__ float fast_tanh(float x) {
    return 1.0f - 2.0f * __builtin_amdgcn_rcpf(1.0f + __expf(2.0f * x));
}

// ---------------- weight packing (fp32 -> bf16, fused/padded layouts) ----------
// wgp[l][o(128)][k(224)]: k 0..63 = conv tap t-d, 64..127 = tap t, 128..207 = cond, 208..223 = 0
// wzp[l][r(128)][k(64)]:  r 0..63 = skip_w rows, 64..127 = out_w rows
__global__ void k_pack(const float* __restrict__ conv_w, const float* __restrict__ cond_w,
                       const float* __restrict__ skip_w, const float* __restrict__ out_w,
                       const float* __restrict__ first_w, const float* __restrict__ last1_w,
                       const float* __restrict__ last2_w,
                       unsigned short* __restrict__ wgp, unsigned short* __restrict__ wzp,
                       unsigned short* __restrict__ fwp, unsigned short* __restrict__ l1p,
                       unsigned short* __restrict__ l2p) {
    int i = blockIdx.x * blockDim.x + threadIdx.x;
    if (i < 860160) {  // wgp: 30*128*224
        int l = i / 28672, r = i % 28672;
        int o = r / 224, k = r % 224;
        float v;
        if (k < 64)       v = conv_w[(((size_t)l * 128 + o) * 64 + k) * 2 + 0];
        else if (k < 128) v = conv_w[(((size_t)l * 128 + o) * 64 + (k - 64)) * 2 + 1];
        else if (k < 208) v = cond_w[((size_t)l * 128 + o) * 80 + (k - 128)];
        else              v = 0.0f;
        wgp[i] = f2b(v);
        return;
    }
    i -= 860160;
    if (i < 245760) {  // wzp: 30*128*64
        int l = i / 8192, rr = (i % 8192) / 64, k = i % 64;
        float v = (rr < 64) ? skip_w[((size_t)l * 64 + rr) * 64 + k]
                            : out_w[((size_t)l * 64 + (rr - 64)) * 64 + k];
        wzp[i] = f2b(v);
        return;
    }
    i -= 245760;
    if (i < 16384) { fwp[i] = f2b(first_w[i]); return; }   // 64*256
    i -= 16384;
    if (i < 4096) { l1p[i] = f2b(last1_w[i]); return; }    // 64*64
    i -= 4096;
    if (i < 16384) { l2p[i] = f2b(last2_w[i]); return; }   // 256*64
}

// ---------------- upsample network ----------------
__global__ void k_convin(const float* __restrict__ c, const float* __restrict__ w,
                         float* __restrict__ c1) {
    int idx = blockIdx.x * blockDim.x + threadIdx.x;
    if (idx >= BATCH * 80 * 400) return;
    int f = idx % 400;
    int o = (idx / 400) % 80;
    int b = idx / (400 * 80);
    const float* cb = c + (size_t)b * 80 * 400 + f;
    const float* wr = w + o * 80;
    float acc = 0.f;
    #pragma unroll 8
    for (int j = 0; j < 80; ++j) acc += wr[j] * cb[(size_t)j * 400];
    c1[idx] = acc;
}

// repeat x10 + 21-tap smooth via piecewise-constant decomposition (3 src values)
__global__ void k_up0(const float* __restrict__ c1, const float* __restrict__ w,
                      float* __restrict__ c2) {
    int idx = blockIdx.x * blockDim.x + threadIdx.x;
    if (idx >= BATCH * 80 * 4000) return;
    int t = idx % 4000;
    int ch = idx / 4000;
    int u = t / 10, r = t - u * 10;
    float w0 = 0.f, w1 = 0.f, w2 = 0.f;
    #pragma unroll
    for (int j = 0; j < 21; ++j) {
        float wj = w[j];
        int a = r - 10 + j;
        if (a < 0) w0 += wj;
        else if (a < 10) w1 += wj;
        else w2 += wj;
    }
    const float* src = c1 + (size_t)ch * 400;
    float s0 = (u >= 1) ? src[u - 1] : 0.f;
    float s1 = src[u];
    float s2 = (u + 1 < 400) ? src[u + 1] : 0.f;
    c2[idx] = w0 * s0 + w1 * s1 + w2 * s2;
}

// repeat x8 + 17-tap smooth, output bf16 t-major [b][t][96] (ch 80..95 zeroed pad)
__global__ __launch_bounds__(256) void k_up1b(const float* __restrict__ c2,
                                              const float* __restrict__ w,
                                              unsigned short* __restrict__ cupb) {
    __shared__ float S[80][13];
    __shared__ float W[8][4];
    const int b = blockIdx.y, t0 = blockIdx.x * 64;
    const int tid = threadIdx.x;
    const int u0 = t0 >> 3;

    for (int i = tid; i < 800; i += 256) {
        int ch = i / 10, uu = i % 10;
        int u = u0 - 1 + uu;
        float v = 0.f;
        if (u >= 0 && u < 4000) v = c2[((size_t)b * 80 + ch) * 4000 + u];
        S[ch][uu] = v;
    }
    if (tid < 24) {
        int r = tid / 3, k = tid % 3;
        int jlo = (k == 0) ? 0 : (k == 1 ? 8 - r : 16 - r);
        int jhi = (k == 0) ? 7 - r : (k == 1 ? 15 - r : 16);
        float a = 0.f;
        for (int j = jlo; j <= jhi; ++j) a += w[j];
        W[r][k] = a;
    }
    __syncthreads();

    unsigned short* ob = cupb + ((size_t)b * T_TOTAL + t0) * 96;
    for (int i = tid; i < 64 * 96; i += 256) {
        int ch = i % 96;
        int tl = i / 96;
        float acc = 0.f;
        if (ch < 80) {
            int r = tl & 7, ub = tl >> 3;
            acc = W[r][0] * S[ch][ub] + W[r][1] * S[ch][ub + 1] + W[r][2] * S[ch][ub + 2];
        }
        ob[i] = f2b(acc);
    }
}

// ---------------- first 1x1 conv (MFMA), TTF=32 tile for occupancy -----------
#define XFS 266
__global__ __launch_bounds__(256, 8) void k_first(
    const float* __restrict__ x, const unsigned short* __restrict__ fwp,
    const float* __restrict__ fb, float* __restrict__ h0) {
    __shared__ unsigned short Xf[TTF * XFS];
    const int b = blockIdx.y, t0 = blockIdx.x * TTF, tid = threadIdx.x;
    const int lane = tid & 63;
    const int wv = __builtin_amdgcn_readfirstlane(tid >> 6);
    const int l15 = lane & 15, q = lane >> 4;

    for (int i = tid; i < 2048; i += 256) {
        int ch = i >> 3;
        int t4 = (i & 7) << 2;
        const float* xr = x + ((size_t)b * 256 + ch) * T_TOTAL + t0 + t4;
        float4 u = *(const float4*)xr;
        int base = t4 * XFS + ch;
        Xf[base + 0 * XFS] = f2b(u.x);
        Xf[base + 1 * XFS] = f2b(u.y);
        Xf[base + 2 * XFS] = f2b(u.z);
        Xf[base + 3 * XFS] = f2b(u.w);
    }
    __syncthreads();

    f32x4 acc[2] = {};
    const unsigned short* wr = fwp + (size_t)(16 * wv + l15) * 256;
    #pragma unroll
    for (int ks = 0; ks < 8; ++ks) {
        bf16x8 aA = ld_bf8(wr + ks * 32 + q * 8);
        #pragma unroll
        for (int tt = 0; tt < 2; ++tt) {
            bf16x8 bb = ld_bf8(&Xf[(tt * 16 + l15) * XFS + ks * 32 + q * 8]);
            acc[tt] = __builtin_amdgcn_mfma_f32_16x16x32_bf16(aA, bb, acc[tt], 0, 0, 0);
        }
    }
    const float4 fbv = *(const float4*)&fb[16 * wv + 4 * q];
    float* hob = h0 + (size_t)b * T_TOTAL * 64;
    #pragma unroll
    for (int tt = 0; tt < 2; ++tt) {
        size_t base = (size_t)(t0 + tt * 16 + l15) * 64 + 16 * wv + 4 * q;
        float4 ho;
        ho.x = acc[tt][0] + fbv.x;
        ho.y = acc[tt][1] + fbv.y;
        ho.z = acc[tt][2] + fbv.z;
        ho.w = acc[tt][3] + fbv.w;
        *(float4*)(hob + base) = ho;
    }
}

// ---------------- fused WaveNet layer, TTL=32 tile for occupancy -------------
// LDS 18.9KB -> 8 blocks/CU; __launch_bounds__(256,8) holds VGPR <= 64 so
// occupancy is LDS-limited at 32 waves/CU (was 16 at TT=64 / 37.9KB).
__global__ __launch_bounds__(256, 8) void k_layer(
    const float* __restrict__ h_in, float* __restrict__ h_out,
    float* __restrict__ skips, const unsigned short* __restrict__ cupb,
    const unsigned short* __restrict__ wgp_l, const unsigned short* __restrict__ wzp_l,
    const float* __restrict__ cb_l, const float* __restrict__ ob_l,
    const float* __restrict__ sb_l, int d, int first) {
    __shared__ unsigned short Xl[TTL * 224];
    __shared__ unsigned short zs[TTL * 72];
    const int b = blockIdx.y, t0 = blockIdx.x * TTL, tid = threadIdx.x;
    const int lane = tid & 63;
    const int wv = __builtin_amdgcn_readfirstlane(tid >> 6);
    const int l15 = lane & 15, q = lane >> 4;

    const float* hb = h_in + (size_t)b * T_TOTAL * 64;
    // stage taps (fp32 -> bf16): 32 rows x 8 ch-groups = 256 slots, 1/thread
    {
        int i = tid;
        int t = i >> 3, cb8 = (i & 7) << 3;
        const float4* p1 = (const float4*)(hb + (size_t)(t0 + t) * 64 + cb8);
        float4 u0 = p1[0], u1 = p1[1];
        uint4v v1;
        v1.x = f2b2(u0.x, u0.y); v1.y = f2b2(u0.z, u0.w);
        v1.z = f2b2(u1.x, u1.y); v1.w = f2b2(u1.z, u1.w);
        *(uint4v*)&Xl[t * 224 + 64 + cb8] = v1;
        int td = t0 + t - d;
        uint4v v0 = {0u, 0u, 0u, 0u};
        if (td >= 0) {
            const float4* p0 = (const float4*)(hb + (size_t)td * 64 + cb8);
            float4 w0 = p0[0], w1 = p0[1];
            v0.x = f2b2(w0.x, w0.y); v0.y = f2b2(w0.z, w0.w);
            v0.z = f2b2(w1.x, w1.y); v0.w = f2b2(w1.z, w1.w);
        }
        *(uint4v*)&Xl[t * 224 + cb8] = v0;
    }
    // stage conditioning (already bf16, zero-padded ch 80..95): 32*12 = 384
    const unsigned short* cbb = cupb + (size_t)b * T_TOTAL * 96;
    for (int i = tid; i < 384; i += 256) {
        int t = i / 12, j = (i % 12) << 3;
        *(uint4v*)&Xl[t * 224 + 128 + j] = *(const uint4v*)&cbb[(size_t)(t0 + t) * 96 + j];
    }
    __syncthreads();

    // gate GEMM: wave wv owns rows {16wv..+15} (a) and {64+16wv..+15} (g), 2 t-tiles
    f32x4 accA[2] = {}, accG[2] = {};
    const unsigned short* wrow_a = wgp_l + (size_t)(16 * wv + l15) * 224;
    const unsigned short* wrow_g = wgp_l + (size_t)(64 + 16 * wv + l15) * 224;
    #pragma unroll
    for (int ks = 0; ks < 7; ++ks) {
        bf16x8 aA = ld_bf8(wrow_a + ks * 32 + q * 8);
        bf16x8 aG = ld_bf8(wrow_g + ks * 32 + q * 8);
        #pragma unroll
        for (int tt = 0; tt < 2; ++tt) {
            bf16x8 bb = ld_bf8(&Xl[(tt * 16 + l15) * 224 + ks * 32 + q * 8]);
            accA[tt] = __builtin_amdgcn_mfma_f32_16x16x32_bf16(aA, bb, accA[tt], 0, 0, 0);
            accG[tt] = __builtin_amdgcn_mfma_f32_16x16x32_bf16(aG, bb, accG[tt], 0, 0, 0);
        }
    }
    // activation -> z tile in LDS
    const float4 cbA = *(const float4*)&cb_l[16 * wv + 4 * q];
    const float4 cbG = *(const float4*)&cb_l[64 + 16 * wv + 4 * q];
    #pragma unroll
    for (int tt = 0; tt < 2; ++tt) {
        int t = tt * 16 + l15;
        float z0 = fast_tanh(accA[tt][0] + cbA.x) * fast_sigmoid(accG[tt][0] + cbG.x);
        float z1 = fast_tanh(accA[tt][1] + cbA.y) * fast_sigmoid(accG[tt][1] + cbG.y);
        float z2 = fast_tanh(accA[tt][2] + cbA.z) * fast_sigmoid(accG[tt][2] + cbG.z);
        float z3 = fast_tanh(accA[tt][3] + cbA.w) * fast_sigmoid(accG[tt][3] + cbG.w);
        uint2v zv;
        zv.x = f2b2(z0, z1);
        zv.y = f2b2(z2, z3);
        *(uint2v*)&zs[t * 72 + 16 * wv + 4 * q] = zv;
    }
    __syncthreads();

    // z GEMM: skip rows 16wv.., out rows 64+16wv..
    f32x4 accS[2] = {}, accO[2] = {};
    const unsigned short* zrow_s = wzp_l + (size_t)(16 * wv + l15) * 64;
    const unsigned short* zrow_o = wzp_l + (size_t)(64 + 16 * wv + l15) * 64;
    #pragma unroll
    for (int ks = 0; ks < 2; ++ks) {
        bf16x8 aS = ld_bf8(zrow_s + ks * 32 + q * 8);
        bf16x8 aO = ld_bf8(zrow_o + ks * 32 + q * 8);
        #pragma unroll
        for (int tt = 0; tt < 2; ++tt) {
            bf16x8 bb = ld_bf8(&zs[(tt * 16 + l15) * 72 + ks * 32 + q * 8]);
            accS[tt] = __builtin_amdgcn_mfma_f32_16x16x32_bf16(aS, bb, accS[tt], 0, 0, 0);
            accO[tt] = __builtin_amdgcn_mfma_f32_16x16x32_bf16(aO, bb, accO[tt], 0, 0, 0);
        }
    }
    const float4 sbv = *(const float4*)&sb_l[16 * wv + 4 * q];
    const float4 obv = *(const float4*)&ob_l[16 * wv + 4 * q];
    float* hob = h_out + (size_t)b * T_TOTAL * 64;
    float* skb = skips + (size_t)b * T_TOTAL * 64;
    #pragma unroll
    for (int tt = 0; tt < 2; ++tt) {
        size_t base = (size_t)(t0 + tt * 16 + l15) * 64 + 16 * wv + 4 * q;
        float4 hi = *(const float4*)(hb + base);
        float4 ho;
        ho.x = hi.x + accO[tt][0] + obv.x;
        ho.y = hi.y + accO[tt][1] + obv.y;
        ho.z = hi.z + accO[tt][2] + obv.z;
        ho.w = hi.w + accO[tt][3] + obv.w;
        *(float4*)(hob + base) = ho;
        float4 sv;
        if (first) {
            sv.x = accS[tt][0] + sbv.x;
            sv.y = accS[tt][1] + sbv.y;
            sv.z = accS[tt][2] + sbv.z;
            sv.w = accS[tt][3] + sbv.w;
        } else {
            float4 sp = *(const float4*)(skb + base);
            sv.x = sp.x + accS[tt][0] + sbv.x;
            sv.y = sp.y + accS[tt][1] + sbv.y;
            sv.z = sp.z + accS[tt][2] + sbv.z;
            sv.w = sp.w + accS[tt][3] + sbv.w;
        }
        *(float4*)(skb + base) = sv;
    }
}

// ---------------- last layers (MFMA): relu -> 1x1 -> relu -> 1x1 -------------
__global__ __launch_bounds__(256) void k_last(
    const float* __restrict__ skips, const unsigned short* __restrict__ l1p,
    const float* __restrict__ b1, const unsigned short* __restrict__ l2p,
    const float* __restrict__ b2, float* __restrict__ out) {
    __shared__ unsigned short sp[64 * 72];
    __shared__ unsigned short o2s[64 * 72];
    const int b = blockIdx.y, t0 = blockIdx.x * TT, tid = threadIdx.x;
    const int lane = tid & 63;
    const int wv = __builtin_amdgcn_readfirstlane(tid >> 6);
    const int l15 = lane & 15, q = lane >> 4;

    const float* skb = skips + (size_t)b * T_TOTAL * 64;
    for (int i = tid; i < 512; i += 256) {
        int t = i >> 3, cb8 = (i & 7) << 3;
        const float4* p = (const float4*)(skb + (size_t)(t0 + t) * 64 + cb8);
        float4 u0 = p[0], u1 = p[1];
        uint4v v;
        v.x = f2b2(fmaxf(u0.x, 0.f), fmaxf(u0.y, 0.f));
        v.y = f2b2(fmaxf(u0.z, 0.f), fmaxf(u0.w, 0.f));
        v.z = f2b2(fmaxf(u1.x, 0.f), fmaxf(u1.y, 0.f));
        v.w = f2b2(fmaxf(u1.z, 0.f), fmaxf(u1.w, 0.f));
        *(uint4v*)&sp[t * 72 + cb8] = v;
    }
    __syncthreads();

    f32x4 a1[4] = {};
    const unsigned short* w1r = l1p + (size_t)(16 * wv + l15) * 64;
    #pragma unroll
    for (int ks = 0; ks < 2; ++ks) {
        bf16x8 aA = ld_bf8(w1r + ks * 32 + q * 8);
        #pragma unroll
        for (int tt = 0; tt < 4; ++tt) {
            bf16x8 bb = ld_bf8(&sp[(tt * 16 + l15) * 72 + ks * 32 + q * 8]);
            a1[tt] = __builtin_amdgcn_mfma_f32_16x16x32_bf16(aA, bb, a1[tt], 0, 0, 0);
        }
    }
    const float4 b1v = *(const float4*)&b1[16 * wv + 4 * q];
    #pragma unroll
    for (int tt = 0; tt < 4; ++tt) {
        int t = tt * 16 + l15;
        float z0 = fmaxf(a1[tt][0] + b1v.x, 0.f);
        float z1 = fmaxf(a1[tt][1] + b1v.y, 0.f);
        float z2 = fmaxf(a1[tt][2] + b1v.z, 0.f);
        float z3 = fmaxf(a1[tt][3] + b1v.w, 0.f);
        uint2v zv;
        zv.x = f2b2(z0, z1);
        zv.y = f2b2(z2, z3);
        *(uint2v*)&o2s[t * 72 + 16 * wv + 4 * q] = zv;
    }
    __syncthreads();

    f32x4 a2[4][4] = {};
    #pragma unroll
    for (int ks = 0; ks < 2; ++ks) {
        bf16x8 aw[4];
        #pragma unroll
        for (int j = 0; j < 4; ++j)
            aw[j] = ld_bf8(l2p + (size_t)(64 * wv + 16 * j + l15) * 64 + ks * 32 + q * 8);
        #pragma unroll
        for (int tt = 0; tt < 4; ++tt) {
            bf16x8 bb = ld_bf8(&o2s[(tt * 16 + l15) * 72 + ks * 32 + q * 8]);
            #pragma unroll
            for (int j = 0; j < 4; ++j)
                a2[j][tt] = __builtin_amdgcn_mfma_f32_16x16x32_bf16(aw[j], bb, a2[j][tt], 0, 0, 0);
        }
    }
    float* ob = out + (size_t)b * 256 * T_TOTAL;
    #pragma unroll
    for (int j = 0; j < 4; ++j) {
        int o0 = 64 * wv + 16 * j + 4 * q;
        float4 b2v = *(const float4*)&b2[o0];
        #pragma unroll
        for (int tt = 0; tt < 4; ++tt) {
            int t = t0 + tt * 16 + l15;
            ob[(size_t)(o0 + 0) * T_TOTAL + t] = a2[j][tt][0] + b2v.x;
            ob[(size_t)(o0 + 1) * T_TOTAL + t] = a2[j][tt][1] + b2v.y;
            ob[(size_t)(o0 + 2) * T_TOTAL + t] = a2[j][tt][2] + b2v.z;
            ob[(size_t)(o0 + 3) * T_TOTAL + t] = a2[j][tt][3] + b2v.w;
        }
    }
}

extern "C" void kernel_launch(void* const* d_in, const int* in_sizes, int n_in,
                              void* d_out, int out_size, void* d_ws, size_t ws_size,
                              hipStream_t stream) {
    const float* x         = (const float*)d_in[0];
    const float* c         = (const float*)d_in[1];
    const float* first_w   = (const float*)d_in[2];
    const float* first_b   = (const float*)d_in[3];
    const float* conv_w    = (const float*)d_in[4];
    const float* conv_b    = (const float*)d_in[5];
    const float* cond_w    = (const float*)d_in[6];
    const float* out_w     = (const float*)d_in[7];
    const float* out_b     = (const float*)d_in[8];
    const float* skip_w    = (const float*)d_in[9];
    const float* skip_b    = (const float*)d_in[10];
    const float* last1_w   = (const float*)d_in[11];
    const float* last1_b   = (const float*)d_in[12];
    const float* last2_w   = (const float*)d_in[13];
    const float* last2_b   = (const float*)d_in[14];
    const float* conv_in_w = (const float*)d_in[15];
    const float* up_w0     = (const float*)d_in[16];
    const float* up_w1     = (const float*)d_in[17];

    unsigned char* base = (unsigned char*)d_ws;
    float* c1            = (float*)(base + 0);                   //    512,000
    float* c2            = (float*)(base + 512000);              //  5,120,000
    unsigned short* cupb = (unsigned short*)(base + 5632000);    // 24,576,000
    float* hA            = (float*)(base + 30208000);            // 32,768,000
    float* hB            = (float*)(base + 62976000);            // 32,768,000
    float* skips         = (float*)(base + 95744000);            // 32,768,000
    unsigned short* wgp  = (unsigned short*)(base + 128512000);  //  1,720,320
    unsigned short* wzp  = (unsigned short*)(base + 130232320);  //    491,520
    unsigned short* fwp  = (unsigned short*)(base + 130723840);  //     32,768
    unsigned short* l1p  = (unsigned short*)(base + 130756608);  //      8,192
    unsigned short* l2p  = (unsigned short*)(base + 130764800);  //     32,768

    k_pack<<<(1142784 + 255) / 256, 256, 0, stream>>>(
        conv_w, cond_w, skip_w, out_w, first_w, last1_w, last2_w,
        wgp, wzp, fwp, l1p, l2p);
    k_convin<<<(BATCH * 80 * 400 + 255) / 256, 256, 0, stream>>>(c, conv_in_w, c1);
    k_up0<<<(BATCH * 80 * 4000 + 255) / 256, 256, 0, stream>>>(c1, up_w0, c2);
    dim3 upg(T_TOTAL / 64, BATCH);
    k_up1b<<<upg, 256, 0, stream>>>(c2, up_w1, cupb);

    dim3 gridF(T_TOTAL / TTF, BATCH);
    k_first<<<gridF, 256, 0, stream>>>(x, fwp, first_b, hA);

    dim3 gridL(T_TOTAL / TTL, BATCH);
    float* hin = hA;
    float* hout = hB;
    for (int l = 0; l < 30; ++l) {
        int d = 1 << (l % 10);
        k_layer<<<gridL, 256, 0, stream>>>(
            hin, hout, skips, cupb,
            wgp + (size_t)l * 128 * 224, wzp + (size_t)l * 128 * 64,
            conv_b + (size_t)l * 128, out_b + (size_t)l * 64, skip_b + (size_t)l * 64,
            d, l == 0 ? 1 : 0);
        float* tmp = hin; hin = hout; hout = tmp;
    }

    dim3 grid(T_TOTAL / TT, BATCH);
    k_last<<<grid, 256, 0, stream>>>(skips, l1p, last1_b, l2p, last2_b, (float*)d_out);
}

// Round 8
// 1510.849 us; speedup vs baseline: 3.2688x; 1.0984x over previous
//
#include <hip/hip_runtime.h>
#include <math.h>

#define T_TOTAL 32000
#define BATCH 4
#define TT 64
#define TTL 128
#define TTF 32

typedef __bf16 bf16x8 __attribute__((ext_vector_type(8)));
typedef float f32x4 __attribute__((ext_vector_type(4)));
typedef unsigned int uint4v __attribute__((ext_vector_type(4)));
typedef unsigned int uint2v __attribute__((ext_vector_type(2)));

__device__ __forceinline__ unsigned short f2b(float f) {
    unsigned int u = __float_as_uint(f);
    u += 0x7FFFu + ((u >> 16) & 1u);
    return (unsigned short)(u >> 16);
}
__device__ __forceinline__ unsigned int f2b2(float lo, float hi) {
    return (unsigned int)f2b(lo) | ((unsigned int)f2b(hi) << 16);
}
__device__ __forceinline__ bf16x8 ld_bf8(const unsigned short* p) {
    return __builtin_bit_cast(bf16x8, *(const uint4v*)p);
}
__device__ __forceinline__ float fast_sigmoid(float x) {
    return __builtin_amdgcn_rcpf(1.0f + __expf(-x));
}
__device__ __forceinline__ float fast_tanh(float x) {
    return 1.0f - 2.0f * __builtin_amdgcn_rcpf(1.0f + __expf(2.0f * x));
}

// ---------------- weight packing (fp32 -> bf16, fused/padded layouts) ----------
// wgp[l][o(128)][k(224)]: k 0..63 = conv tap t-d, 64..127 = tap t, 128..207 = cond, 208..223 = 0
// wzp[l][r(128)][k(64)]:  r 0..63 = skip_w rows, 64..127 = out_w rows
__global__ void k_pack(const float* __restrict__ conv_w, const float* __restrict__ cond_w,
                       const float* __restrict__ skip_w, const float* __restrict__ out_w,
                       const float* __restrict__ first_w, const float* __restrict__ last1_w,
                       const float* __restrict__ last2_w,
                       unsigned short* __restrict__ wgp, unsigned short* __restrict__ wzp,
                       unsigned short* __restrict__ fwp, unsigned short* __restrict__ l1p,
                       unsigned short* __restrict__ l2p) {
    int i = blockIdx.x * blockDim.x + threadIdx.x;
    if (i < 860160) {  // wgp: 30*128*224
        int l = i / 28672, r = i % 28672;
        int o = r / 224, k = r % 224;
        float v;
        if (k < 64)       v = conv_w[(((size_t)l * 128 + o) * 64 + k) * 2 + 0];
        else if (k < 128) v = conv_w[(((size_t)l * 128 + o) * 64 + (k - 64)) * 2 + 1];
        else if (k < 208) v = cond_w[((size_t)l * 128 + o) * 80 + (k - 128)];
        else              v = 0.0f;
        wgp[i] = f2b(v);
        return;
    }
    i -= 860160;
    if (i < 245760) {  // wzp: 30*128*64
        int l = i / 8192, rr = (i % 8192) / 64, k = i % 64;
        float v = (rr < 64) ? skip_w[((size_t)l * 64 + rr) * 64 + k]
                            : out_w[((size_t)l * 64 + (rr - 64)) * 64 + k];
        wzp[i] = f2b(v);
        return;
    }
    i -= 245760;
    if (i < 16384) { fwp[i] = f2b(first_w[i]); return; }   // 64*256
    i -= 16384;
    if (i < 4096) { l1p[i] = f2b(last1_w[i]); return; }    // 64*64
    i -= 4096;
    if (i < 16384) { l2p[i] = f2b(last2_w[i]); return; }   // 256*64
}

// ---------------- upsample network ----------------
__global__ void k_convin(const float* __restrict__ c, const float* __restrict__ w,
                         float* __restrict__ c1) {
    int idx = blockIdx.x * blockDim.x + threadIdx.x;
    if (idx >= BATCH * 80 * 400) return;
    int f = idx % 400;
    int o = (idx / 400) % 80;
    int b = idx / (400 * 80);
    const float* cb = c + (size_t)b * 80 * 400 + f;
    const float* wr = w + o * 80;
    float acc = 0.f;
    #pragma unroll 8
    for (int j = 0; j < 80; ++j) acc += wr[j] * cb[(size_t)j * 400];
    c1[idx] = acc;
}

// repeat x10 + 21-tap smooth via piecewise-constant decomposition (3 src values)
__global__ void k_up0(const float* __restrict__ c1, const float* __restrict__ w,
                      float* __restrict__ c2) {
    int idx = blockIdx.x * blockDim.x + threadIdx.x;
    if (idx >= BATCH * 80 * 4000) return;
    int t = idx % 4000;
    int ch = idx / 4000;
    int u = t / 10, r = t - u * 10;
    float w0 = 0.f, w1 = 0.f, w2 = 0.f;
    #pragma unroll
    for (int j = 0; j < 21; ++j) {
        float wj = w[j];
        int a = r - 10 + j;
        if (a < 0) w0 += wj;
        else if (a < 10) w1 += wj;
        else w2 += wj;
    }
    const float* src = c1 + (size_t)ch * 400;
    float s0 = (u >= 1) ? src[u - 1] : 0.f;
    float s1 = src[u];
    float s2 = (u + 1 < 400) ? src[u + 1] : 0.f;
    c2[idx] = w0 * s0 + w1 * s1 + w2 * s2;
}

// repeat x8 + 17-tap smooth, output bf16 t-major [b][t][96] (ch 80..95 zeroed pad)
__global__ __launch_bounds__(256) void k_up1b(const float* __restrict__ c2,
                                              const float* __restrict__ w,
                                              unsigned short* __restrict__ cupb) {
    __shared__ float S[80][13];
    __shared__ float W[8][4];
    const int b = blockIdx.y, t0 = blockIdx.x * 64;
    const int tid = threadIdx.x;
    const int u0 = t0 >> 3;

    for (int i = tid; i < 800; i += 256) {
        int ch = i / 10, uu = i % 10;
        int u = u0 - 1 + uu;
        float v = 0.f;
        if (u >= 0 && u < 4000) v = c2[((size_t)b * 80 + ch) * 4000 + u];
        S[ch][uu] = v;
    }
    if (tid < 24) {
        int r = tid / 3, k = tid % 3;
        int jlo = (k == 0) ? 0 : (k == 1 ? 8 - r : 16 - r);
        int jhi = (k == 0) ? 7 - r : (k == 1 ? 15 - r : 16);
        float a = 0.f;
        for (int j = jlo; j <= jhi; ++j) a += w[j];
        W[r][k] = a;
    }
    __syncthreads();

    unsigned short* ob = cupb + ((size_t)b * T_TOTAL + t0) * 96;
    for (int i = tid; i < 64 * 96; i += 256) {
        int ch = i % 96;
        int tl = i / 96;
        float acc = 0.f;
        if (ch < 80) {
            int r = tl & 7, ub = tl >> 3;
            acc = W[r][0] * S[ch][ub] + W[r][1] * S[ch][ub + 1] + W[r][2] * S[ch][ub + 2];
        }
        ob[i] = f2b(acc);
    }
}

// ---------------- first 1x1 conv (MFMA), TTF=32 tile -------------------------
#define XFS 266
__global__ __launch_bounds__(256, 8) void k_first(
    const float* __restrict__ x, const unsigned short* __restrict__ fwp,
    const float* __restrict__ fb, float* __restrict__ h0) {
    __shared__ unsigned short Xf[TTF * XFS];
    const int b = blockIdx.y, t0 = blockIdx.x * TTF, tid = threadIdx.x;
    const int lane = tid & 63;
    const int wv = __builtin_amdgcn_readfirstlane(tid >> 6);
    const int l15 = lane & 15, q = lane >> 4;

    for (int i = tid; i < 2048; i += 256) {
        int ch = i >> 3;
        int t4 = (i & 7) << 2;
        const float* xr = x + ((size_t)b * 256 + ch) * T_TOTAL + t0 + t4;
        float4 u = *(const float4*)xr;
        int base = t4 * XFS + ch;
        Xf[base + 0 * XFS] = f2b(u.x);
        Xf[base + 1 * XFS] = f2b(u.y);
        Xf[base + 2 * XFS] = f2b(u.z);
        Xf[base + 3 * XFS] = f2b(u.w);
    }
    __syncthreads();

    f32x4 acc[2] = {};
    const unsigned short* wr = fwp + (size_t)(16 * wv + l15) * 256;
    #pragma unroll
    for (int ks = 0; ks < 8; ++ks) {
        bf16x8 aA = ld_bf8(wr + ks * 32 + q * 8);
        #pragma unroll
        for (int tt = 0; tt < 2; ++tt) {
            bf16x8 bb = ld_bf8(&Xf[(tt * 16 + l15) * XFS + ks * 32 + q * 8]);
            acc[tt] = __builtin_amdgcn_mfma_f32_16x16x32_bf16(aA, bb, acc[tt], 0, 0, 0);
        }
    }
    const float4 fbv = *(const float4*)&fb[16 * wv + 4 * q];
    float* hob = h0 + (size_t)b * T_TOTAL * 64;
    #pragma unroll
    for (int tt = 0; tt < 2; ++tt) {
        size_t base = (size_t)(t0 + tt * 16 + l15) * 64 + 16 * wv + 4 * q;
        float4 ho;
        ho.x = acc[tt][0] + fbv.x;
        ho.y = acc[tt][1] + fbv.y;
        ho.z = acc[tt][2] + fbv.z;
        ho.w = acc[tt][3] + fbv.w;
        *(float4*)(hob + base) = ho;
    }
}

// ---------------- fused WaveNet layer, TTL=128 tile --------------------------
// Bigger tile: halves per-layer weight re-reads (each block loads the 57KB gate
// weight tile once per 128 t instead of per 64 t), halves barrier drains per
// byte, doubles per-wave MFMA ILP. LDS 75.7KB -> 2 blocks/CU.
__global__ __launch_bounds__(256, 2) void k_layer(
    const float* __restrict__ h_in, float* __restrict__ h_out,
    float* __restrict__ skips, const unsigned short* __restrict__ cupb,
    const unsigned short* __restrict__ wgp_l, const unsigned short* __restrict__ wzp_l,
    const float* __restrict__ cb_l, const float* __restrict__ ob_l,
    const float* __restrict__ sb_l, int d, int first) {
    __shared__ unsigned short Xl[TTL * 224];  // 57,344 B
    __shared__ unsigned short zs[TTL * 72];   // 18,432 B
    const int b = blockIdx.y, t0 = blockIdx.x * TTL, tid = threadIdx.x;
    const int lane = tid & 63;
    const int wv = __builtin_amdgcn_readfirstlane(tid >> 6);
    const int l15 = lane & 15, q = lane >> 4;

    const float* hb = h_in + (size_t)b * T_TOTAL * 64;
    // stage taps (fp32 -> bf16): 128 rows x 8 ch-groups = 1024 slots
    for (int i = tid; i < 1024; i += 256) {
        int t = i >> 3, cb8 = (i & 7) << 3;
        const float4* p1 = (const float4*)(hb + (size_t)(t0 + t) * 64 + cb8);
        float4 u0 = p1[0], u1 = p1[1];
        uint4v v1;
        v1.x = f2b2(u0.x, u0.y); v1.y = f2b2(u0.z, u0.w);
        v1.z = f2b2(u1.x, u1.y); v1.w = f2b2(u1.z, u1.w);
        *(uint4v*)&Xl[t * 224 + 64 + cb8] = v1;
        int td = t0 + t - d;
        uint4v v0 = {0u, 0u, 0u, 0u};
        if (td >= 0) {
            const float4* p0 = (const float4*)(hb + (size_t)td * 64 + cb8);
            float4 w0 = p0[0], w1 = p0[1];
            v0.x = f2b2(w0.x, w0.y); v0.y = f2b2(w0.z, w0.w);
            v0.z = f2b2(w1.x, w1.y); v0.w = f2b2(w1.z, w1.w);
        }
        *(uint4v*)&Xl[t * 224 + cb8] = v0;
    }
    // stage conditioning (already bf16, zero-padded ch 80..95): 128*12 = 1536
    const unsigned short* cbb = cupb + (size_t)b * T_TOTAL * 96;
    for (int i = tid; i < 1536; i += 256) {
        int t = i / 12, j = (i % 12) << 3;
        *(uint4v*)&Xl[t * 224 + 128 + j] = *(const uint4v*)&cbb[(size_t)(t0 + t) * 96 + j];
    }
    __syncthreads();

    // gate GEMM: wave wv owns rows {16wv..+15} (a) and {64+16wv..+15} (g), 8 t-tiles
    f32x4 accA[8] = {}, accG[8] = {};
    const unsigned short* wrow_a = wgp_l + (size_t)(16 * wv + l15) * 224;
    const unsigned short* wrow_g = wgp_l + (size_t)(64 + 16 * wv + l15) * 224;
    #pragma unroll
    for (int ks = 0; ks < 7; ++ks) {
        bf16x8 aA = ld_bf8(wrow_a + ks * 32 + q * 8);
        bf16x8 aG = ld_bf8(wrow_g + ks * 32 + q * 8);
        #pragma unroll
        for (int tt = 0; tt < 8; ++tt) {
            bf16x8 bb = ld_bf8(&Xl[(tt * 16 + l15) * 224 + ks * 32 + q * 8]);
            accA[tt] = __builtin_amdgcn_mfma_f32_16x16x32_bf16(aA, bb, accA[tt], 0, 0, 0);
            accG[tt] = __builtin_amdgcn_mfma_f32_16x16x32_bf16(aG, bb, accG[tt], 0, 0, 0);
        }
    }
    // activation -> z tile in LDS
    const float4 cbA = *(const float4*)&cb_l[16 * wv + 4 * q];
    const float4 cbG = *(const float4*)&cb_l[64 + 16 * wv + 4 * q];
    #pragma unroll
    for (int tt = 0; tt < 8; ++tt) {
        int t = tt * 16 + l15;
        float z0 = fast_tanh(accA[tt][0] + cbA.x) * fast_sigmoid(accG[tt][0] + cbG.x);
        float z1 = fast_tanh(accA[tt][1] + cbA.y) * fast_sigmoid(accG[tt][1] + cbG.y);
        float z2 = fast_tanh(accA[tt][2] + cbA.z) * fast_sigmoid(accG[tt][2] + cbG.z);
        float z3 = fast_tanh(accA[tt][3] + cbA.w) * fast_sigmoid(accG[tt][3] + cbG.w);
        uint2v zv;
        zv.x = f2b2(z0, z1);
        zv.y = f2b2(z2, z3);
        *(uint2v*)&zs[t * 72 + 16 * wv + 4 * q] = zv;
    }
    __syncthreads();

    // z GEMM: skip rows 16wv.., out rows 64+16wv..
    f32x4 accS[8] = {}, accO[8] = {};
    const unsigned short* zrow_s = wzp_l + (size_t)(16 * wv + l15) * 64;
    const unsigned short* zrow_o = wzp_l + (size_t)(64 + 16 * wv + l15) * 64;
    #pragma unroll
    for (int ks = 0; ks < 2; ++ks) {
        bf16x8 aS = ld_bf8(zrow_s + ks * 32 + q * 8);
        bf16x8 aO = ld_bf8(zrow_o + ks * 32 + q * 8);
        #pragma unroll
        for (int tt = 0; tt < 8; ++tt) {
            bf16x8 bb = ld_bf8(&zs[(tt * 16 + l15) * 72 + ks * 32 + q * 8]);
            accS[tt] = __builtin_amdgcn_mfma_f32_16x16x32_bf16(aS, bb, accS[tt], 0, 0, 0);
            accO[tt] = __builtin_amdgcn_mfma_f32_16x16x32_bf16(aO, bb, accO[tt], 0, 0, 0);
        }
    }
    const float4 sbv = *(const float4*)&sb_l[16 * wv + 4 * q];
    const float4 obv = *(const float4*)&ob_l[16 * wv + 4 * q];
    float* hob = h_out + (size_t)b * T_TOTAL * 64;
    float* skb = skips + (size_t)b * T_TOTAL * 64;
    #pragma unroll
    for (int tt = 0; tt < 8; ++tt) {
        size_t base = (size_t)(t0 + tt * 16 + l15) * 64 + 16 * wv + 4 * q;
        float4 hi = *(const float4*)(hb + base);
        float4 ho;
        ho.x = hi.x + accO[tt][0] + obv.x;
        ho.y = hi.y + accO[tt][1] + obv.y;
        ho.z = hi.z + accO[tt][2] + obv.z;
        ho.w = hi.w + accO[tt][3] + obv.w;
        *(float4*)(hob + base) = ho;
        float4 sv;
        if (first) {
            sv.x = accS[tt][0] + sbv.x;
            sv.y = accS[tt][1] + sbv.y;
            sv.z = accS[tt][2] + sbv.z;
            sv.w = accS[tt][3] + sbv.w;
        } else {
            float4 sp = *(const float4*)(skb + base);
            sv.x = sp.x + accS[tt][0] + sbv.x;
            sv.y = sp.y + accS[tt][1] + sbv.y;
            sv.z = sp.z + accS[tt][2] + sbv.z;
            sv.w = sp.w + accS[tt][3] + sbv.w;
        }
        *(float4*)(skb + base) = sv;
    }
}

// ---------------- last layers (MFMA): relu -> 1x1 -> relu -> 1x1 -------------
__global__ __launch_bounds__(256) void k_last(
    const float* __restrict__ skips, const unsigned short* __restrict__ l1p,
    const float* __restrict__ b1, const unsigned short* __restrict__ l2p,
    const float* __restrict__ b2, float* __restrict__ out) {
    __shared__ unsigned short sp[64 * 72];
    __shared__ unsigned short o2s[64 * 72];
    const int b = blockIdx.y, t0 = blockIdx.x * TT, tid = threadIdx.x;
    const int lane = tid & 63;
    const int wv = __builtin_amdgcn_readfirstlane(tid >> 6);
    const int l15 = lane & 15, q = lane >> 4;

    const float* skb = skips + (size_t)b * T_TOTAL * 64;
    for (int i = tid; i < 512; i += 256) {
        int t = i >> 3, cb8 = (i & 7) << 3;
        const float4* p = (const float4*)(skb + (size_t)(t0 + t) * 64 + cb8);
        float4 u0 = p[0], u1 = p[1];
        uint4v v;
        v.x = f2b2(fmaxf(u0.x, 0.f), fmaxf(u0.y, 0.f));
        v.y = f2b2(fmaxf(u0.z, 0.f), fmaxf(u0.w, 0.f));
        v.z = f2b2(fmaxf(u1.x, 0.f), fmaxf(u1.y, 0.f));
        v.w = f2b2(fmaxf(u1.z, 0.f), fmaxf(u1.w, 0.f));
        *(uint4v*)&sp[t * 72 + cb8] = v;
    }
    __syncthreads();

    f32x4 a1[4] = {};
    const unsigned short* w1r = l1p + (size_t)(16 * wv + l15) * 64;
    #pragma unroll
    for (int ks = 0; ks < 2; ++ks) {
        bf16x8 aA = ld_bf8(w1r + ks * 32 + q * 8);
        #pragma unroll
        for (int tt = 0; tt < 4; ++tt) {
            bf16x8 bb = ld_bf8(&sp[(tt * 16 + l15) * 72 + ks * 32 + q * 8]);
            a1[tt] = __builtin_amdgcn_mfma_f32_16x16x32_bf16(aA, bb, a1[tt], 0, 0, 0);
        }
    }
    const float4 b1v = *(const float4*)&b1[16 * wv + 4 * q];
    #pragma unroll
    for (int tt = 0; tt < 4; ++tt) {
        int t = tt * 16 + l15;
        float z0 = fmaxf(a1[tt][0] + b1v.x, 0.f);
        float z1 = fmaxf(a1[tt][1] + b1v.y, 0.f);
        float z2 = fmaxf(a1[tt][2] + b1v.z, 0.f);
        float z3 = fmaxf(a1[tt][3] + b1v.w, 0.f);
        uint2v zv;
        zv.x = f2b2(z0, z1);
        zv.y = f2b2(z2, z3);
        *(uint2v*)&o2s[t * 72 + 16 * wv + 4 * q] = zv;
    }
    __syncthreads();

    f32x4 a2[4][4] = {};
    #pragma unroll
    for (int ks = 0; ks < 2; ++ks) {
        bf16x8 aw[4];
        #pragma unroll
        for (int j = 0; j < 4; ++j)
            aw[j] = ld_bf8(l2p + (size_t)(64 * wv + 16 * j + l15) * 64 + ks * 32 + q * 8);
        #pragma unroll
        for (int tt = 0; tt < 4; ++tt) {
            bf16x8 bb = ld_bf8(&o2s[(tt * 16 + l15) * 72 + ks * 32 + q * 8]);
            #pragma unroll
            for (int j = 0; j < 4; ++j)
                a2[j][tt] = __builtin_amdgcn_mfma_f32_16x16x32_bf16(aw[j], bb, a2[j][tt], 0, 0, 0);
        }
    }
    float* ob = out + (size_t)b * 256 * T_TOTAL;
    #pragma unroll
    for (int j = 0; j < 4; ++j) {
        int o0 = 64 * wv + 16 * j + 4 * q;
        float4 b2v = *(const float4*)&b2[o0];
        #pragma unroll
        for (int tt = 0; tt < 4; ++tt) {
            int t = t0 + tt * 16 + l15;
            ob[(size_t)(o0 + 0) * T_TOTAL + t] = a2[j][tt][0] + b2v.x;
            ob[(size_t)(o0 + 1) * T_TOTAL + t] = a2[j][tt][1] + b2v.y;
            ob[(size_t)(o0 + 2) * T_TOTAL + t] = a2[j][tt][2] + b2v.z;
            ob[(size_t)(o0 + 3) * T_TOTAL + t] = a2[j][tt][3] + b2v.w;
        }
    }
}

extern "C" void kernel_launch(void* const* d_in, const int* in_sizes, int n_in,
                              void* d_out, int out_size, void* d_ws, size_t ws_size,
                              hipStream_t stream) {
    const float* x         = (const float*)d_in[0];
    const float* c         = (const float*)d_in[1];
    const float* first_w   = (const float*)d_in[2];
    const float* first_b   = (const float*)d_in[3];
    const float* conv_w    = (const float*)d_in[4];
    const float* conv_b    = (const float*)d_in[5];
    const float* cond_w    = (const float*)d_in[6];
    const float* out_w     = (const float*)d_in[7];
    const float* out_b     = (const float*)d_in[8];
    const float* skip_w    = (const float*)d_in[9];
    const float* skip_b    = (const float*)d_in[10];
    const float* last1_w   = (const float*)d_in[11];
    const float* last1_b   = (const float*)d_in[12];
    const float* last2_w   = (const float*)d_in[13];
    const float* last2_b   = (const float*)d_in[14];
    const float* conv_in_w = (const float*)d_in[15];
    const float* up_w0     = (const float*)d_in[16];
    const float* up_w1     = (const float*)d_in[17];

    unsigned char* base = (unsigned char*)d_ws;
    float* c1            = (float*)(base + 0);                   //    512,000
    float* c2            = (float*)(base + 512000);              //  5,120,000
    unsigned short* cupb = (unsigned short*)(base + 5632000);    // 24,576,000
    float* hA            = (float*)(base + 30208000);            // 32,768,000
    float* hB            = (float*)(base + 62976000);            // 32,768,000
    float* skips         = (float*)(base + 95744000);            // 32,768,000
    unsigned short* wgp  = (unsigned short*)(base + 128512000);  //  1,720,320
    unsigned short* wzp  = (unsigned short*)(base + 130232320);  //    491,520
    unsigned short* fwp  = (unsigned short*)(base + 130723840);  //     32,768
    unsigned short* l1p  = (unsigned short*)(base + 130756608);  //      8,192
    unsigned short* l2p  = (unsigned short*)(base + 130764800);  //     32,768

    k_pack<<<(1142784 + 255) / 256, 256, 0, stream>>>(
        conv_w, cond_w, skip_w, out_w, first_w, last1_w, last2_w,
        wgp, wzp, fwp, l1p, l2p);
    k_convin<<<(BATCH * 80 * 400 + 255) / 256, 256, 0, stream>>>(c, conv_in_w, c1);
    k_up0<<<(BATCH * 80 * 4000 + 255) / 256, 256, 0, stream>>>(c1, up_w0, c2);
    dim3 upg(T_TOTAL / 64, BATCH);
    k_up1b<<<upg, 256, 0, stream>>>(c2, up_w1, cupb);

    dim3 gridF(T_TOTAL / TTF, BATCH);
    k_first<<<gridF, 256, 0, stream>>>(x, fwp, first_b, hA);

    dim3 gridL(T_TOTAL / TTL, BATCH);
    float* hin = hA;
    float* hout = hB;
    for (int l = 0; l < 30; ++l) {
        int d = 1 << (l % 10);
        k_layer<<<gridL, 256, 0, stream>>>(
            hin, hout, skips, cupb,
            wgp + (size_t)l * 128 * 224, wzp + (size_t)l * 128 * 64,
            conv_b + (size_t)l * 128, out_b + (size_t)l * 64, skip_b + (size_t)l * 64,
            d, l == 0 ? 1 : 0);
        float* tmp = hin; hin = hout; hout = tmp;
    }

    dim3 grid(T_TOTAL / TT, BATCH);
    k_last<<<grid, 256, 0, stream>>>(skips, l1p, last1_b, l2p, last2_b, (float*)d_out);
}

// Round 9
// 1440.661 us; speedup vs baseline: 3.4280x; 1.0487x over previous
//
#include <hip/hip_runtime.h>
#include <math.h>

#define T_TOTAL 32000
#define BATCH 4
#define TT 64
#define TTF 32
#define X1S 232   // LDS row stride (shorts) for 224-wide tiles: 464B -> 2-way banks
#define X2S 136   // LDS row stride for 128-wide tap tiles: 272B -> 2-way banks

typedef __bf16 bf16x8 __attribute__((ext_vector_type(8)));
typedef float f32x4 __attribute__((ext_vector_type(4)));
typedef unsigned int uint4v __attribute__((ext_vector_type(4)));
typedef unsigned int uint2v __attribute__((ext_vector_type(2)));

__device__ __forceinline__ unsigned short f2b(float f) {
    unsigned int u = __float_as_uint(f);
    u += 0x7FFFu + ((u >> 16) & 1u);
    return (unsigned short)(u >> 16);
}
__device__ __forceinline__ unsigned int f2b2(float lo, float hi) {
    return (unsigned int)f2b(lo) | ((unsigned int)f2b(hi) << 16);
}
__device__ __forceinline__ bf16x8 ld_bf8(const unsigned short* p) {
    return __builtin_bit_cast(bf16x8, *(const uint4v*)p);
}
__device__ __forceinline__ float fast_sigmoid(float x) {
    return __builtin_amdgcn_rcpf(1.0f + __expf(-x));
}
__device__ __forceinline__ float fast_tanh(float x) {
    return 1.0f - 2.0f * __builtin_amdgcn_rcpf(1.0f + __expf(2.0f * x));
}
#define MFMA(a, b, c) __builtin_amdgcn_mfma_f32_16x16x32_bf16((a), (b), (c), 0, 0, 0)

// ---------------- weight packing (fp32 -> bf16, fused/padded layouts) ----------
// wgp[l][o(128)][k(224)]: k 0..63 = conv tap t-d, 64..127 = tap t, 128..207 = cond, 208..223 = 0
// wzp[l][r(128)][k(64)]:  r 0..63 = skip_w rows, 64..127 = out_w rows
__global__ void k_pack(const float* __restrict__ conv_w, const float* __restrict__ cond_w,
                       const float* __restrict__ skip_w, const float* __restrict__ out_w,
                       const float* __restrict__ first_w, const float* __restrict__ last1_w,
                       const float* __restrict__ last2_w,
                       unsigned short* __restrict__ wgp, unsigned short* __restrict__ wzp,
                       unsigned short* __restrict__ fwp, unsigned short* __restrict__ l1p,
                       unsigned short* __restrict__ l2p) {
    int i = blockIdx.x * blockDim.x + threadIdx.x;
    if (i < 860160) {  // wgp: 30*128*224
        int l = i / 28672, r = i % 28672;
        int o = r / 224, k = r % 224;
        float v;
        if (k < 64)       v = conv_w[(((size_t)l * 128 + o) * 64 + k) * 2 + 0];
        else if (k < 128) v = conv_w[(((size_t)l * 128 + o) * 64 + (k - 64)) * 2 + 1];
        else if (k < 208) v = cond_w[((size_t)l * 128 + o) * 80 + (k - 128)];
        else              v = 0.0f;
        wgp[i] = f2b(v);
        return;
    }
    i -= 860160;
    if (i < 245760) {  // wzp: 30*128*64
        int l = i / 8192, rr = (i % 8192) / 64, k = i % 64;
        float v = (rr < 64) ? skip_w[((size_t)l * 64 + rr) * 64 + k]
                            : out_w[((size_t)l * 64 + (rr - 64)) * 64 + k];
        wzp[i] = f2b(v);
        return;
    }
    i -= 245760;
    if (i < 16384) { fwp[i] = f2b(first_w[i]); return; }   // 64*256
    i -= 16384;
    if (i < 4096) { l1p[i] = f2b(last1_w[i]); return; }    // 64*64
    i -= 4096;
    if (i < 16384) { l2p[i] = f2b(last2_w[i]); return; }   // 256*64
}

// ---------------- upsample network ----------------
__global__ void k_convin(const float* __restrict__ c, const float* __restrict__ w,
                         float* __restrict__ c1) {
    int idx = blockIdx.x * blockDim.x + threadIdx.x;
    if (idx >= BATCH * 80 * 400) return;
    int f = idx % 400;
    int o = (idx / 400) % 80;
    int b = idx / (400 * 80);
    const float* cb = c + (size_t)b * 80 * 400 + f;
    const float* wr = w + o * 80;
    float acc = 0.f;
    #pragma unroll 8
    for (int j = 0; j < 80; ++j) acc += wr[j] * cb[(size_t)j * 400];
    c1[idx] = acc;
}

__global__ void k_up0(const float* __restrict__ c1, const float* __restrict__ w,
                      float* __restrict__ c2) {
    int idx = blockIdx.x * blockDim.x + threadIdx.x;
    if (idx >= BATCH * 80 * 4000) return;
    int t = idx % 4000;
    int ch = idx / 4000;
    int u = t / 10, r = t - u * 10;
    float w0 = 0.f, w1 = 0.f, w2 = 0.f;
    #pragma unroll
    for (int j = 0; j < 21; ++j) {
        float wj = w[j];
        int a = r - 10 + j;
        if (a < 0) w0 += wj;
        else if (a < 10) w1 += wj;
        else w2 += wj;
    }
    const float* src = c1 + (size_t)ch * 400;
    float s0 = (u >= 1) ? src[u - 1] : 0.f;
    float s1 = src[u];
    float s2 = (u + 1 < 400) ? src[u + 1] : 0.f;
    c2[idx] = w0 * s0 + w1 * s1 + w2 * s2;
}

__global__ __launch_bounds__(256) void k_up1b(const float* __restrict__ c2,
                                              const float* __restrict__ w,
                                              unsigned short* __restrict__ cupb) {
    __shared__ float S[80][13];
    __shared__ float W[8][4];
    const int b = blockIdx.y, t0 = blockIdx.x * 64;
    const int tid = threadIdx.x;
    const int u0 = t0 >> 3;

    for (int i = tid; i < 800; i += 256) {
        int ch = i / 10, uu = i % 10;
        int u = u0 - 1 + uu;
        float v = 0.f;
        if (u >= 0 && u < 4000) v = c2[((size_t)b * 80 + ch) * 4000 + u];
        S[ch][uu] = v;
    }
    if (tid < 24) {
        int r = tid / 3, k = tid % 3;
        int jlo = (k == 0) ? 0 : (k == 1 ? 8 - r : 16 - r);
        int jhi = (k == 0) ? 7 - r : (k == 1 ? 15 - r : 16);
        float a = 0.f;
        for (int j = jlo; j <= jhi; ++j) a += w[j];
        W[r][k] = a;
    }
    __syncthreads();

    unsigned short* ob = cupb + ((size_t)b * T_TOTAL + t0) * 96;
    for (int i = tid; i < 64 * 96; i += 256) {
        int ch = i % 96;
        int tl = i / 96;
        float acc = 0.f;
        if (ch < 80) {
            int r = tl & 7, ub = tl >> 3;
            acc = W[r][0] * S[ch][ub] + W[r][1] * S[ch][ub + 1] + W[r][2] * S[ch][ub + 2];
        }
        ob[i] = f2b(acc);
    }
}

// ---------------- first 1x1 conv (MFMA), TTF=32 tile -------------------------
#define XFS 266
__global__ __launch_bounds__(256, 8) void k_first(
    const float* __restrict__ x, const unsigned short* __restrict__ fwp,
    const float* __restrict__ fb, float* __restrict__ h0) {
    __shared__ unsigned short Xf[TTF * XFS];
    const int b = blockIdx.y, t0 = blockIdx.x * TTF, tid = threadIdx.x;
    const int lane = tid & 63;
    const int wv = __builtin_amdgcn_readfirstlane(tid >> 6);
    const int l15 = lane & 15, q = lane >> 4;

    for (int i = tid; i < 2048; i += 256) {
        int ch = i >> 3;
        int t4 = (i & 7) << 2;
        const float* xr = x + ((size_t)b * 256 + ch) * T_TOTAL + t0 + t4;
        float4 u = *(const float4*)xr;
        int base = t4 * XFS + ch;
        Xf[base + 0 * XFS] = f2b(u.x);
        Xf[base + 1 * XFS] = f2b(u.y);
        Xf[base + 2 * XFS] = f2b(u.z);
        Xf[base + 3 * XFS] = f2b(u.w);
    }
    __syncthreads();

    f32x4 acc[2] = {};
    const unsigned short* wr = fwp + (size_t)(16 * wv + l15) * 256;
    #pragma unroll
    for (int ks = 0; ks < 8; ++ks) {
        bf16x8 aA = ld_bf8(wr + ks * 32 + q * 8);
        #pragma unroll
        for (int tt = 0; tt < 2; ++tt) {
            bf16x8 bb = ld_bf8(&Xf[(tt * 16 + l15) * XFS + ks * 32 + q * 8]);
            acc[tt] = MFMA(aA, bb, acc[tt]);
        }
    }
    const float4 fbv = *(const float4*)&fb[16 * wv + 4 * q];
    float* hob = h0 + (size_t)b * T_TOTAL * 64;
    #pragma unroll
    for (int tt = 0; tt < 2; ++tt) {
        size_t base = (size_t)(t0 + tt * 16 + l15) * 64 + 16 * wv + 4 * q;
        float4 ho;
        ho.x = acc[tt][0] + fbv.x;
        ho.y = acc[tt][1] + fbv.y;
        ho.z = acc[tt][2] + fbv.z;
        ho.w = acc[tt][3] + fbv.w;
        *(float4*)(hob + base) = ho;
    }
}

// ---------------- single fused WaveNet layer (TT=64, stride-fixed LDS) -------
__global__ __launch_bounds__(256, 4) void k_layer(
    const float* __restrict__ h_in, float* __restrict__ h_out,
    float* __restrict__ skips, const unsigned short* __restrict__ cupb,
    const unsigned short* __restrict__ wgp_l, const unsigned short* __restrict__ wzp_l,
    const float* __restrict__ cb_l, const float* __restrict__ ob_l,
    const float* __restrict__ sb_l, int d, int first) {
    __shared__ __attribute__((aligned(16))) unsigned short Xl[TT * X1S];
    __shared__ __attribute__((aligned(16))) unsigned short zs[TT * 72];
    const int b = blockIdx.y, t0 = blockIdx.x * TT, tid = threadIdx.x;
    const int lane = tid & 63;
    const int wv = __builtin_amdgcn_readfirstlane(tid >> 6);
    const int l15 = lane & 15, q = lane >> 4;

    const float* hb = h_in + (size_t)b * T_TOTAL * 64;
    for (int i = tid; i < 512; i += 256) {
        int t = i >> 3, cb8 = (i & 7) << 3;
        const float4* p1 = (const float4*)(hb + (size_t)(t0 + t) * 64 + cb8);
        float4 u0 = p1[0], u1 = p1[1];
        uint4v v1;
        v1.x = f2b2(u0.x, u0.y); v1.y = f2b2(u0.z, u0.w);
        v1.z = f2b2(u1.x, u1.y); v1.w = f2b2(u1.z, u1.w);
        *(uint4v*)&Xl[t * X1S + 64 + cb8] = v1;
        int td = t0 + t - d;
        uint4v v0 = {0u, 0u, 0u, 0u};
        if (td >= 0) {
            const float4* p0 = (const float4*)(hb + (size_t)td * 64 + cb8);
            float4 w0 = p0[0], w1 = p0[1];
            v0.x = f2b2(w0.x, w0.y); v0.y = f2b2(w0.z, w0.w);
            v0.z = f2b2(w1.x, w1.y); v0.w = f2b2(w1.z, w1.w);
        }
        *(uint4v*)&Xl[t * X1S + cb8] = v0;
    }
    const unsigned short* cbb = cupb + (size_t)b * T_TOTAL * 96;
    for (int i = tid; i < 768; i += 256) {
        int t = i / 12, j = (i % 12) << 3;
        *(uint4v*)&Xl[t * X1S + 128 + j] = *(const uint4v*)&cbb[(size_t)(t0 + t) * 96 + j];
    }
    __syncthreads();

    f32x4 accA[4] = {}, accG[4] = {};
    const unsigned short* wrow_a = wgp_l + (size_t)(16 * wv + l15) * 224;
    const unsigned short* wrow_g = wgp_l + (size_t)(64 + 16 * wv + l15) * 224;
    #pragma unroll
    for (int ks = 0; ks < 7; ++ks) {
        bf16x8 aA = ld_bf8(wrow_a + ks * 32 + q * 8);
        bf16x8 aG = ld_bf8(wrow_g + ks * 32 + q * 8);
        #pragma unroll
        for (int tt = 0; tt < 4; ++tt) {
            bf16x8 bb = ld_bf8(&Xl[(tt * 16 + l15) * X1S + ks * 32 + q * 8]);
            accA[tt] = MFMA(aA, bb, accA[tt]);
            accG[tt] = MFMA(aG, bb, accG[tt]);
        }
    }
    const float4 cbA = *(const float4*)&cb_l[16 * wv + 4 * q];
    const float4 cbG = *(const float4*)&cb_l[64 + 16 * wv + 4 * q];
    #pragma unroll
    for (int tt = 0; tt < 4; ++tt) {
        int t = tt * 16 + l15;
        float z0 = fast_tanh(accA[tt][0] + cbA.x) * fast_sigmoid(accG[tt][0] + cbG.x);
        float z1 = fast_tanh(accA[tt][1] + cbA.y) * fast_sigmoid(accG[tt][1] + cbG.y);
        float z2 = fast_tanh(accA[tt][2] + cbA.z) * fast_sigmoid(accG[tt][2] + cbG.z);
        float z3 = fast_tanh(accA[tt][3] + cbA.w) * fast_sigmoid(accG[tt][3] + cbG.w);
        uint2v zv;
        zv.x = f2b2(z0, z1);
        zv.y = f2b2(z2, z3);
        *(uint2v*)&zs[t * 72 + 16 * wv + 4 * q] = zv;
    }
    __syncthreads();

    f32x4 accS[4] = {}, accO[4] = {};
    const unsigned short* zrow_s = wzp_l + (size_t)(16 * wv + l15) * 64;
    const unsigned short* zrow_o = wzp_l + (size_t)(64 + 16 * wv + l15) * 64;
    #pragma unroll
    for (int ks = 0; ks < 2; ++ks) {
        bf16x8 aS = ld_bf8(zrow_s + ks * 32 + q * 8);
        bf16x8 aO = ld_bf8(zrow_o + ks * 32 + q * 8);
        #pragma unroll
        for (int tt = 0; tt < 4; ++tt) {
            bf16x8 bb = ld_bf8(&zs[(tt * 16 + l15) * 72 + ks * 32 + q * 8]);
            accS[tt] = MFMA(aS, bb, accS[tt]);
            accO[tt] = MFMA(aO, bb, accO[tt]);
        }
    }
    const float4 sbv = *(const float4*)&sb_l[16 * wv + 4 * q];
    const float4 obv = *(const float4*)&ob_l[16 * wv + 4 * q];
    float* hob = h_out + (size_t)b * T_TOTAL * 64;
    float* skb = skips + (size_t)b * T_TOTAL * 64;
    #pragma unroll
    for (int tt = 0; tt < 4; ++tt) {
        size_t base = (size_t)(t0 + tt * 16 + l15) * 64 + 16 * wv + 4 * q;
        float4 hi = *(const float4*)(hb + base);
        float4 ho;
        ho.x = hi.x + accO[tt][0] + obv.x;
        ho.y = hi.y + accO[tt][1] + obv.y;
        ho.z = hi.z + accO[tt][2] + obv.z;
        ho.w = hi.w + accO[tt][3] + obv.w;
        *(float4*)(hob + base) = ho;
        float4 sv;
        if (first) {
            sv.x = accS[tt][0] + sbv.x;
            sv.y = accS[tt][1] + sbv.y;
            sv.z = accS[tt][2] + sbv.z;
            sv.w = accS[tt][3] + sbv.w;
        } else {
            float4 sp = *(const float4*)(skb + base);
            sv.x = sp.x + accS[tt][0] + sbv.x;
            sv.y = sp.y + accS[tt][1] + sbv.y;
            sv.z = sp.z + accS[tt][2] + sbv.z;
            sv.w = sp.w + accS[tt][3] + sbv.w;
        }
        *(float4*)(skb + base) = sv;
    }
}

// ---------------- fused layer PAIR (d2 <= 32), bit-exact ---------------------
// Computes layer l over extended rows [t0-32, t0+64) keeping h_l on-chip, then
// layer l+1 over [t0, t0+64). h_l fp32 lives in X1's dead tap columns (swizzled);
// bf16 taps for layer l+1 in X2. Skip contributions applied in exact seq order.
__global__ __launch_bounds__(256, 2) void k_layer2(
    const float* __restrict__ h_in, float* __restrict__ h_out,
    float* __restrict__ skips, const unsigned short* __restrict__ cupb,
    const unsigned short* __restrict__ wg1, const unsigned short* __restrict__ wg2,
    const unsigned short* __restrict__ wz1, const unsigned short* __restrict__ wz2,
    const float* __restrict__ cb1, const float* __restrict__ cb2,
    const float* __restrict__ ob1, const float* __restrict__ ob2,
    const float* __restrict__ sb1, const float* __restrict__ sb2,
    int d1, int d2, int first) {
    __shared__ __attribute__((aligned(16))) unsigned short X1[96 * X1S];  // 44,544B
    __shared__ __attribute__((aligned(16))) unsigned short ZS[96 * 72];   // 13,824B
    __shared__ __attribute__((aligned(16))) unsigned short X2[64 * X2S];  // 17,408B
    const int b = blockIdx.y, t0 = blockIdx.x * 64, ts = t0 - 32;
    const int tid = threadIdx.x;
    const int lane = tid & 63;
    const int wv = __builtin_amdgcn_readfirstlane(tid >> 6);
    const int l15 = lane & 15, q = lane >> 4;
    const int chb = 16 * wv + 4 * q;
    const int chunk = 4 * wv + q;

    const float* hb = h_in + (size_t)b * T_TOTAL * 64;
    // stage X1 taps (96 rows)
    for (int i = tid; i < 768; i += 256) {
        int r = i >> 3, cb8 = (i & 7) << 3;
        int t = ts + r;
        uint4v v1 = {0u, 0u, 0u, 0u}, v0 = {0u, 0u, 0u, 0u};
        if (t >= 0) {
            const float4* p1 = (const float4*)(hb + (size_t)t * 64 + cb8);
            float4 u0 = p1[0], u1 = p1[1];
            v1.x = f2b2(u0.x, u0.y); v1.y = f2b2(u0.z, u0.w);
            v1.z = f2b2(u1.x, u1.y); v1.w = f2b2(u1.z, u1.w);
        }
        int td = ts + r - d1;
        if (td >= 0) {
            const float4* p0 = (const float4*)(hb + (size_t)td * 64 + cb8);
            float4 w0 = p0[0], w1 = p0[1];
            v0.x = f2b2(w0.x, w0.y); v0.y = f2b2(w0.z, w0.w);
            v0.z = f2b2(w1.x, w1.y); v0.w = f2b2(w1.z, w1.w);
        }
        *(uint4v*)&X1[r * X1S + 64 + cb8] = v1;
        *(uint4v*)&X1[r * X1S + cb8] = v0;
    }
    // stage cond (96 rows)
    const unsigned short* cbb = cupb + (size_t)b * T_TOTAL * 96;
    for (int i = tid; i < 1152; i += 256) {
        int r = i / 12, j = (i % 12) << 3;
        int t = ts + r;
        uint4v cv = {0u, 0u, 0u, 0u};
        if (t >= 0) cv = *(const uint4v*)&cbb[(size_t)t * 96 + j];
        *(uint4v*)&X1[r * X1S + 128 + j] = cv;
    }
    __syncthreads();

    // gate1 over 6 t-tiles
    f32x4 A1[6] = {}, G1[6] = {};
    {
        const unsigned short* wra = wg1 + (size_t)(16 * wv + l15) * 224;
        const unsigned short* wrg = wg1 + (size_t)(64 + 16 * wv + l15) * 224;
        #pragma unroll
        for (int ks = 0; ks < 7; ++ks) {
            bf16x8 aA = ld_bf8(wra + ks * 32 + q * 8);
            bf16x8 aG = ld_bf8(wrg + ks * 32 + q * 8);
            #pragma unroll
            for (int tt = 0; tt < 6; ++tt) {
                bf16x8 bb = ld_bf8(&X1[(tt * 16 + l15) * X1S + ks * 32 + q * 8]);
                A1[tt] = MFMA(aA, bb, A1[tt]);
                G1[tt] = MFMA(aG, bb, G1[tt]);
            }
        }
    }
    {
        const float4 cA = *(const float4*)&cb1[chb];
        const float4 cG = *(const float4*)&cb1[64 + chb];
        #pragma unroll
        for (int tt = 0; tt < 6; ++tt) {
            int r = tt * 16 + l15;
            float z0 = fast_tanh(A1[tt][0] + cA.x) * fast_sigmoid(G1[tt][0] + cG.x);
            float z1 = fast_tanh(A1[tt][1] + cA.y) * fast_sigmoid(G1[tt][1] + cG.y);
            float z2 = fast_tanh(A1[tt][2] + cA.z) * fast_sigmoid(G1[tt][2] + cG.z);
            float z3 = fast_tanh(A1[tt][3] + cA.w) * fast_sigmoid(G1[tt][3] + cG.w);
            uint2v zv;
            zv.x = f2b2(z0, z1);
            zv.y = f2b2(z2, z3);
            *(uint2v*)&ZS[r * 72 + chb] = zv;
        }
    }
    __syncthreads();

    // out1 (6 tiles) + skip1 (output tiles = staged tiles 2..5)
    f32x4 O1[6] = {}, S1[4] = {};
    {
        const unsigned short* zrs = wz1 + (size_t)(16 * wv + l15) * 64;
        const unsigned short* zro = wz1 + (size_t)(64 + 16 * wv + l15) * 64;
        #pragma unroll
        for (int ks = 0; ks < 2; ++ks) {
            bf16x8 aS = ld_bf8(zrs + ks * 32 + q * 8);
            bf16x8 aO = ld_bf8(zro + ks * 32 + q * 8);
            #pragma unroll
            for (int tt = 0; tt < 6; ++tt) {
                bf16x8 bb = ld_bf8(&ZS[(tt * 16 + l15) * 72 + ks * 32 + q * 8]);
                O1[tt] = MFMA(aO, bb, O1[tt]);
                if (tt >= 2) S1[tt - 2] = MFMA(aS, bb, S1[tt - 2]);
            }
        }
    }
    // epilogue1: h_l = h_in + O1 + ob1 (fp32); stash HF (fp32) + X2 taps (bf16)
    {
        const float4 ov = *(const float4*)&ob1[chb];
        #pragma unroll
        for (int tt = 0; tt < 6; ++tt) {
            int r = tt * 16 + l15;
            int t = ts + r;
            float4 hl = make_float4(0.f, 0.f, 0.f, 0.f);
            if (t >= 0) {
                float4 hi = *(const float4*)(hb + (size_t)t * 64 + chb);
                hl.x = hi.x + O1[tt][0] + ov.x;
                hl.y = hi.y + O1[tt][1] + ov.y;
                hl.z = hi.z + O1[tt][2] + ov.z;
                hl.w = hi.w + O1[tt][3] + ov.w;
            }
            uint2v hbv;
            hbv.x = f2b2(hl.x, hl.y);
            hbv.y = f2b2(hl.z, hl.w);
            if (r >= 32) {
                int swz = chunk ^ (r & 15);
                *(float4*)&X1[r * X1S + 8 * swz] = hl;               // HF (cols 0..127)
                *(uint2v*)&X2[(r - 32) * X2S + 64 + chb] = hbv;      // tap t
            }
            int rr = r - 32 + d2;                                    // tap t-d2 target
            if (rr >= 0 && rr < 64) *(uint2v*)&X2[rr * X2S + chb] = hbv;
        }
    }
    __syncthreads();

    // gate2 (4 tiles): K 0..127 from X2, K 128..223 (cond) from X1 rows+32
    f32x4 A2[4] = {}, G2[4] = {};
    {
        const unsigned short* wra = wg2 + (size_t)(16 * wv + l15) * 224;
        const unsigned short* wrg = wg2 + (size_t)(64 + 16 * wv + l15) * 224;
        #pragma unroll
        for (int ks = 0; ks < 4; ++ks) {
            bf16x8 aA = ld_bf8(wra + ks * 32 + q * 8);
            bf16x8 aG = ld_bf8(wrg + ks * 32 + q * 8);
            #pragma unroll
            for (int tt = 0; tt < 4; ++tt) {
                bf16x8 bb = ld_bf8(&X2[(tt * 16 + l15) * X2S + ks * 32 + q * 8]);
                A2[tt] = MFMA(aA, bb, A2[tt]);
                G2[tt] = MFMA(aG, bb, G2[tt]);
            }
        }
        #pragma unroll
        for (int ks = 4; ks < 7; ++ks) {
            bf16x8 aA = ld_bf8(wra + ks * 32 + q * 8);
            bf16x8 aG = ld_bf8(wrg + ks * 32 + q * 8);
            #pragma unroll
            for (int tt = 0; tt < 4; ++tt) {
                bf16x8 bb = ld_bf8(&X1[(tt * 16 + l15 + 32) * X1S + 128 + (ks - 4) * 32 + q * 8]);
                A2[tt] = MFMA(aA, bb, A2[tt]);
                G2[tt] = MFMA(aG, bb, G2[tt]);
            }
        }
    }
    {
        const float4 cA = *(const float4*)&cb2[chb];
        const float4 cG = *(const float4*)&cb2[64 + chb];
        #pragma unroll
        for (int tt = 0; tt < 4; ++tt) {
            int r = tt * 16 + l15;
            float z0 = fast_tanh(A2[tt][0] + cA.x) * fast_sigmoid(G2[tt][0] + cG.x);
            float z1 = fast_tanh(A2[tt][1] + cA.y) * fast_sigmoid(G2[tt][1] + cG.y);
            float z2 = fast_tanh(A2[tt][2] + cA.z) * fast_sigmoid(G2[tt][2] + cG.z);
            float z3 = fast_tanh(A2[tt][3] + cA.w) * fast_sigmoid(G2[tt][3] + cG.w);
            uint2v zv;
            zv.x = f2b2(z0, z1);
            zv.y = f2b2(z2, z3);
            *(uint2v*)&ZS[r * 72 + chb] = zv;
        }
    }
    __syncthreads();

    // out2 + skip2 (4 tiles) and final epilogue
    f32x4 O2[4] = {}, S2[4] = {};
    {
        const unsigned short* zrs = wz2 + (size_t)(16 * wv + l15) * 64;
        const unsigned short* zro = wz2 + (size_t)(64 + 16 * wv + l15) * 64;
        #pragma unroll
        for (int ks = 0; ks < 2; ++ks) {
            bf16x8 aS = ld_bf8(zrs + ks * 32 + q * 8);
            bf16x8 aO = ld_bf8(zro + ks * 32 + q * 8);
            #pragma unroll
            for (int tt = 0; tt < 4; ++tt) {
                bf16x8 bb = ld_bf8(&ZS[(tt * 16 + l15) * 72 + ks * 32 + q * 8]);
                S2[tt] = MFMA(aS, bb, S2[tt]);
                O2[tt] = MFMA(aO, bb, O2[tt]);
            }
        }
    }
    {
        const float4 o2v = *(const float4*)&ob2[chb];
        const float4 s1v = *(const float4*)&sb1[chb];
        const float4 s2v = *(const float4*)&sb2[chb];
        float* hob = h_out + (size_t)b * T_TOTAL * 64;
        float* skb = skips + (size_t)b * T_TOTAL * 64;
        #pragma unroll
        for (int tt = 0; tt < 4; ++tt) {
            int r = 32 + tt * 16 + l15;
            int t = t0 + tt * 16 + l15;
            int swz = chunk ^ (r & 15);
            float4 hl = *(const float4*)&X1[r * X1S + 8 * swz];
            size_t base = (size_t)t * 64 + chb;
            float4 ho;
            ho.x = hl.x + O2[tt][0] + o2v.x;
            ho.y = hl.y + O2[tt][1] + o2v.y;
            ho.z = hl.z + O2[tt][2] + o2v.z;
            ho.w = hl.w + O2[tt][3] + o2v.w;
            *(float4*)(hob + base) = ho;
            float4 sv;
            if (first) {
                sv.x = S1[tt][0] + s1v.x;
                sv.y = S1[tt][1] + s1v.y;
                sv.z = S1[tt][2] + s1v.z;
                sv.w = S1[tt][3] + s1v.w;
            } else {
                float4 sp = *(const float4*)(skb + base);
                sv.x = sp.x + S1[tt][0] + s1v.x;
                sv.y = sp.y + S1[tt][1] + s1v.y;
                sv.z = sp.z + S1[tt][2] + s1v.z;
                sv.w = sp.w + S1[tt][3] + s1v.w;
            }
            sv.x = sv.x + S2[tt][0] + s2v.x;
            sv.y = sv.y + S2[tt][1] + s2v.y;
            sv.z = sv.z + S2[tt][2] + s2v.z;
            sv.w = sv.w + S2[tt][3] + s2v.w;
            *(float4*)(skb + base) = sv;
        }
    }
}

// ---------------- last layers (MFMA): relu -> 1x1 -> relu -> 1x1 -------------
__global__ __launch_bounds__(256) void k_last(
    const float* __restrict__ skips, const unsigned short* __restrict__ l1p,
    const float* __restrict__ b1, const unsigned short* __restrict__ l2p,
    const float* __restrict__ b2, float* __restrict__ out) {
    __shared__ __attribute__((aligned(16))) unsigned short sp[64 * 72];
    __shared__ __attribute__((aligned(16))) unsigned short o2s[64 * 72];
    const int b = blockIdx.y, t0 = blockIdx.x * TT, tid = threadIdx.x;
    const int lane = tid & 63;
    const int wv = __builtin_amdgcn_readfirstlane(tid >> 6);
    const int l15 = lane & 15, q = lane >> 4;

    const float* skb = skips + (size_t)b * T_TOTAL * 64;
    for (int i = tid; i < 512; i += 256) {
        int t = i >> 3, cb8 = (i & 7) << 3;
        const float4* p = (const float4*)(skb + (size_t)(t0 + t) * 64 + cb8);
        float4 u0 = p[0], u1 = p[1];
        uint4v v;
        v.x = f2b2(fmaxf(u0.x, 0.f), fmaxf(u0.y, 0.f));
        v.y = f2b2(fmaxf(u0.z, 0.f), fmaxf(u0.w, 0.f));
        v.z = f2b2(fmaxf(u1.x, 0.f), fmaxf(u1.y, 0.f));
        v.w = f2b2(fmaxf(u1.z, 0.f), fmaxf(u1.w, 0.f));
        *(uint4v*)&sp[t * 72 + cb8] = v;
    }
    __syncthreads();

    f32x4 a1[4] = {};
    const unsigned short* w1r = l1p + (size_t)(16 * wv + l15) * 64;
    #pragma unroll
    for (int ks = 0; ks < 2; ++ks) {
        bf16x8 aA = ld_bf8(w1r + ks * 32 + q * 8);
        #pragma unroll
        for (int tt = 0; tt < 4; ++tt) {
            bf16x8 bb = ld_bf8(&sp[(tt * 16 + l15) * 72 + ks * 32 + q * 8]);
            a1[tt] = MFMA(aA, bb, a1[tt]);
        }
    }
    const float4 b1v = *(const float4*)&b1[16 * wv + 4 * q];
    #pragma unroll
    for (int tt = 0; tt < 4; ++tt) {
        int t = tt * 16 + l15;
        float z0 = fmaxf(a1[tt][0] + b1v.x, 0.f);
        float z1 = fmaxf(a1[tt][1] + b1v.y, 0.f);
        float z2 = fmaxf(a1[tt][2] + b1v.z, 0.f);
        float z3 = fmaxf(a1[tt][3] + b1v.w, 0.f);
        uint2v zv;
        zv.x = f2b2(z0, z1);
        zv.y = f2b2(z2, z3);
        *(uint2v*)&o2s[t * 72 + 16 * wv + 4 * q] = zv;
    }
    __syncthreads();

    f32x4 a2[4][4] = {};
    #pragma unroll
    for (int ks = 0; ks < 2; ++ks) {
        bf16x8 aw[4];
        #pragma unroll
        for (int j = 0; j < 4; ++j)
            aw[j] = ld_bf8(l2p + (size_t)(64 * wv + 16 * j + l15) * 64 + ks * 32 + q * 8);
        #pragma unroll
        for (int tt = 0; tt < 4; ++tt) {
            bf16x8 bb = ld_bf8(&o2s[(tt * 16 + l15) * 72 + ks * 32 + q * 8]);
            #pragma unroll
            for (int j = 0; j < 4; ++j)
                a2[j][tt] = MFMA(aw[j], bb, a2[j][tt]);
        }
    }
    float* ob = out + (size_t)b * 256 * T_TOTAL;
    #pragma unroll
    for (int j = 0; j < 4; ++j) {
        int o0 = 64 * wv + 16 * j + 4 * q;
        float4 b2v = *(const float4*)&b2[o0];
        #pragma unroll
        for (int tt = 0; tt < 4; ++tt) {
            int t = t0 + tt * 16 + l15;
            ob[(size_t)(o0 + 0) * T_TOTAL + t] = a2[j][tt][0] + b2v.x;
            ob[(size_t)(o0 + 1) * T_TOTAL + t] = a2[j][tt][1] + b2v.y;
            ob[(size_t)(o0 + 2) * T_TOTAL + t] = a2[j][tt][2] + b2v.z;
            ob[(size_t)(o0 + 3) * T_TOTAL + t] = a2[j][tt][3] + b2v.w;
        }
    }
}

extern "C" void kernel_launch(void* const* d_in, const int* in_sizes, int n_in,
                              void* d_out, int out_size, void* d_ws, size_t ws_size,
                              hipStream_t stream) {
    const float* x         = (const float*)d_in[0];
    const float* c         = (const float*)d_in[1];
    const float* first_w   = (const float*)d_in[2];
    const float* first_b   = (const float*)d_in[3];
    const float* conv_w    = (const float*)d_in[4];
    const float* conv_b    = (const float*)d_in[5];
    const float* cond_w    = (const float*)d_in[6];
    const float* out_w     = (const float*)d_in[7];
    const float* out_b     = (const float*)d_in[8];
    const float* skip_w    = (const float*)d_in[9];
    const float* skip_b    = (const float*)d_in[10];
    const float* last1_w   = (const float*)d_in[11];
    const float* last1_b   = (const float*)d_in[12];
    const float* last2_w   = (const float*)d_in[13];
    const float* last2_b   = (const float*)d_in[14];
    const float* conv_in_w = (const float*)d_in[15];
    const float* up_w0     = (const float*)d_in[16];
    const float* up_w1     = (const float*)d_in[17];

    unsigned char* base = (unsigned char*)d_ws;
    float* c1            = (float*)(base + 0);                   //    512,000
    float* c2            = (float*)(base + 512000);              //  5,120,000
    unsigned short* cupb = (unsigned short*)(base + 5632000);    // 24,576,000
    float* hA            = (float*)(base + 30208000);            // 32,768,000
    float* hB            = (float*)(base + 62976000);            // 32,768,000
    float* skips         = (float*)(base + 95744000);            // 32,768,000
    unsigned short* wgp  = (unsigned short*)(base + 128512000);  //  1,720,320
    unsigned short* wzp  = (unsigned short*)(base + 130232320);  //    491,520
    unsigned short* fwp  = (unsigned short*)(base + 130723840);  //     32,768
    unsigned short* l1p  = (unsigned short*)(base + 130756608);  //      8,192
    unsigned short* l2p  = (unsigned short*)(base + 130764800);  //     32,768

    k_pack<<<(1142784 + 255) / 256, 256, 0, stream>>>(
        conv_w, cond_w, skip_w, out_w, first_w, last1_w, last2_w,
        wgp, wzp, fwp, l1p, l2p);
    k_convin<<<(BATCH * 80 * 400 + 255) / 256, 256, 0, stream>>>(c, conv_in_w, c1);
    k_up0<<<(BATCH * 80 * 4000 + 255) / 256, 256, 0, stream>>>(c1, up_w0, c2);
    dim3 upg(T_TOTAL / 64, BATCH);
    k_up1b<<<upg, 256, 0, stream>>>(c2, up_w1, cupb);

    dim3 gridF(T_TOTAL / TTF, BATCH);
    k_first<<<gridF, 256, 0, stream>>>(x, fwp, first_b, hA);

    dim3 grid(T_TOTAL / TT, BATCH);
    float* hin = hA;
    float* hout = hB;
    for (int s = 0; s < 3; ++s) {
        // fused pairs: (d1,d2) = (1,2), (4,8), (16,32)
        for (int p = 0; p < 3; ++p) {
            int l = s * 10 + 2 * p;
            int d1 = 1 << (2 * p);
            k_layer2<<<grid, 256, 0, stream>>>(
                hin, hout, skips, cupb,
                wgp + (size_t)l * 28672, wgp + (size_t)(l + 1) * 28672,
                wzp + (size_t)l * 8192, wzp + (size_t)(l + 1) * 8192,
                conv_b + (size_t)l * 128, conv_b + (size_t)(l + 1) * 128,
                out_b + (size_t)l * 64, out_b + (size_t)(l + 1) * 64,
                skip_b + (size_t)l * 64, skip_b + (size_t)(l + 1) * 64,
                d1, 2 * d1, (l == 0) ? 1 : 0);
            float* tmp = hin; hin = hout; hout = tmp;
        }
        // singles: d = 64, 128, 256, 512
        for (int j = 6; j < 10; ++j) {
            int l = s * 10 + j;
            int d = 1 << j;
            k_layer<<<grid, 256, 0, stream>>>(
                hin, hout, skips, cupb,
                wgp + (size_t)l * 28672, wzp + (size_t)l * 8192,
                conv_b + (size_t)l * 128, out_b + (size_t)l * 64,
                skip_b + (size_t)l * 64, d, 0);
            float* tmp = hin; hin = hout; hout = tmp;
        }
    }

    k_last<<<grid, 256, 0, stream>>>(skips, l1p, last1_b, l2p, last2_b, (float*)d_out);
}